// Round 8
// baseline (1330.253 us; speedup 1.0000x reference)
//
#include <hip/hip_runtime.h>

#define FLTMAX 3.402823466e+38f
#define DEV __device__ __forceinline__

typedef unsigned short u16;
typedef unsigned int u32;
typedef __bf16 bf16_t;
typedef bf16_t bf16x8 __attribute__((ext_vector_type(8)));
typedef float f32x4 __attribute__((ext_vector_type(4)));

union U16x8 { uint4 u; bf16x8 b; };

DEV float trf(float v, float a, float b) { return fmaxf(fmaf(v, a, b), 0.f); }

// round-to-nearest-even fp32 -> bf16 bits (finite inputs)
DEV u16 f2bf(float f) {
    u32 u = __float_as_uint(f);
    return (u16)((u + 0x7FFFu + ((u >> 16) & 1u)) >> 16);
}

// ================= CSR build =================
__global__ __launch_bounds__(256) void hist_k(const int* __restrict__ dst,
                                              int* __restrict__ deg, int E) {
    int e = blockIdx.x * 256 + threadIdx.x;
    if (e >= E) return;
    atomicAdd(&deg[dst[e]], 1);
}

__global__ __launch_bounds__(256) void scan_block_k(const int* __restrict__ deg,
                                                    int* __restrict__ ptr,
                                                    int* __restrict__ bsum, int n) {
    __shared__ int ls[256];
    int i = blockIdx.x * 256 + threadIdx.x;
    int v = (i < n) ? deg[i] : 0;
    ls[threadIdx.x] = v;
    __syncthreads();
#pragma unroll
    for (int off = 1; off < 256; off <<= 1) {
        int a = (threadIdx.x >= off) ? ls[threadIdx.x - off] : 0;
        __syncthreads();
        ls[threadIdx.x] += a;
        __syncthreads();
    }
    if (i < n) ptr[i] = ls[threadIdx.x] - v;
    if (threadIdx.x == 255) bsum[blockIdx.x] = ls[255];
}

__global__ __launch_bounds__(512) void scan_bsum_k(int* __restrict__ bsum, int nb) {
    __shared__ int ls[512];
    int t = threadIdx.x;
    int v = (t < nb) ? bsum[t] : 0;
    ls[t] = v;
    __syncthreads();
#pragma unroll
    for (int off = 1; off < 512; off <<= 1) {
        int a = (t >= off) ? ls[t - off] : 0;
        __syncthreads();
        ls[t] += a;
        __syncthreads();
    }
    if (t < nb) bsum[t] = ls[t] - v;
}

__global__ __launch_bounds__(256) void scan_add_k(int* __restrict__ ptr,
                                                  int* __restrict__ pos,
                                                  const int* __restrict__ bsum,
                                                  int n, int E) {
    int i = blockIdx.x * 256 + threadIdx.x;
    if (i == 0) ptr[n] = E;
    if (i < n) {
        int p = ptr[i] + bsum[blockIdx.x];
        ptr[i] = p;
        pos[i] = p;
    }
}

__global__ __launch_bounds__(256) void csr_fill_k(const int* __restrict__ src,
                                                  const int* __restrict__ dst,
                                                  int* __restrict__ pos,
                                                  int* __restrict__ csr, int E) {
    int e = blockIdx.x * 256 + threadIdx.x;
    if (e >= E) return;
    int p = atomicAdd(&pos[dst[e]], 1);
    csr[p] = src[e];
}

// ====== fp32 gather min (layer-1 x, D=32) ======
__global__ __launch_bounds__(256) void gather_min32_k(
    const float* __restrict__ feat, const int* __restrict__ ptr,
    const int* __restrict__ csr, float* __restrict__ agg, int n) {
    const int lane = threadIdx.x & 63;
    const int wave = (blockIdx.x * 256 + threadIdx.x) >> 6;
    const int node = wave * 2 + (lane >> 5);
    if (node >= n) return;
    const int fl = lane & 31;
    int e = ptr[node];
    const int end = ptr[node + 1];
    const bool empty = (e == end);
    float m = FLTMAX;
    for (; e + 3 < end; e += 4) {
        float v0 = feat[(size_t)csr[e] * 32 + fl];
        float v1 = feat[(size_t)csr[e + 1] * 32 + fl];
        float v2 = feat[(size_t)csr[e + 2] * 32 + fl];
        float v3 = feat[(size_t)csr[e + 3] * 32 + fl];
        m = fminf(m, fminf(fminf(v0, v1), fminf(v2, v3)));
    }
    for (; e < end; e++) m = fminf(m, feat[(size_t)csr[e] * 32 + fl]);
    agg[(size_t)node * 32 + fl] = empty ? 0.f : m;
}

// ====== fp32 gather min D=128 with fused BN+ReLU, 8 rows in flight ======
__global__ __launch_bounds__(256) void gather_min128_k(
    const float* __restrict__ feat, const int* __restrict__ ptr,
    const int* __restrict__ csr, const float* __restrict__ coef,
    float* __restrict__ agg, int n) {
    const int lane = threadIdx.x & 63;
    const int node = (blockIdx.x * 256 + threadIdx.x) >> 6;
    if (node >= n) return;
    const int fl = lane * 2;
    const float ca0 = coef[fl], ca1 = coef[fl + 1];
    const float cb0 = coef[128 + fl], cb1 = coef[128 + fl + 1];
    int e = ptr[node];
    const int end = ptr[node + 1];
    const bool empty = (e == end);
    float m0 = FLTMAX, m1 = FLTMAX;
    for (; e + 7 < end; e += 8) {
        int s[8];
#pragma unroll
        for (int j = 0; j < 8; j++) s[j] = csr[e + j];
        float2 v[8];
#pragma unroll
        for (int j = 0; j < 8; j++) v[j] = *(const float2*)(feat + (size_t)s[j] * 128 + fl);
#pragma unroll
        for (int j = 0; j < 8; j++) {
            m0 = fminf(m0, trf(v[j].x, ca0, cb0));
            m1 = fminf(m1, trf(v[j].y, ca1, cb1));
        }
    }
    for (; e + 3 < end; e += 4) {
        const float2 v0 = *(const float2*)(feat + (size_t)csr[e] * 128 + fl);
        const float2 v1 = *(const float2*)(feat + (size_t)csr[e + 1] * 128 + fl);
        const float2 v2 = *(const float2*)(feat + (size_t)csr[e + 2] * 128 + fl);
        const float2 v3 = *(const float2*)(feat + (size_t)csr[e + 3] * 128 + fl);
        m0 = fminf(m0, fminf(fminf(trf(v0.x, ca0, cb0), trf(v1.x, ca0, cb0)),
                             fminf(trf(v2.x, ca0, cb0), trf(v3.x, ca0, cb0))));
        m1 = fminf(m1, fminf(fminf(trf(v0.y, ca1, cb1), trf(v1.y, ca1, cb1)),
                             fminf(trf(v2.y, ca1, cb1), trf(v3.y, ca1, cb1))));
    }
    for (; e < end; e++) {
        const float2 v = *(const float2*)(feat + (size_t)csr[e] * 128 + fl);
        m0 = fminf(m0, trf(v.x, ca0, cb0));
        m1 = fminf(m1, trf(v.y, ca1, cb1));
    }
    float2 o;
    o.x = empty ? 0.f : m0;
    o.y = empty ? 0.f : m1;
    *(float2*)(agg + (size_t)node * 128 + fl) = o;
}

// ====== bf16 gather min over A_cat right half -> left half, 8 rows in flight ======
__global__ __launch_bounds__(256) void gather_bf_k(
    u16* __restrict__ Acat, const int* __restrict__ ptr,
    const int* __restrict__ csr, int n) {
    const int lane = threadIdx.x & 63;
    const int node = (blockIdx.x * 256 + threadIdx.x) >> 6;
    if (node >= n) return;
    const int fl = lane * 2;
    int e = ptr[node];
    const int end = ptr[node + 1];
    u32 outv = 0;
    if (e != end) {
        float m0 = FLTMAX, m1 = FLTMAX;
        for (; e + 7 < end; e += 8) {
            int s[8];
#pragma unroll
            for (int j = 0; j < 8; j++) s[j] = csr[e + j];
            u32 v[8];
#pragma unroll
            for (int j = 0; j < 8; j++) v[j] = *(const u32*)(Acat + (size_t)s[j] * 256 + 128 + fl);
#pragma unroll
            for (int j = 0; j < 8; j++) {
                m0 = fminf(m0, __uint_as_float(v[j] << 16));
                m1 = fminf(m1, __uint_as_float(v[j] & 0xffff0000u));
            }
        }
        for (; e < end; e++) {
            u32 v = *(const u32*)(Acat + (size_t)csr[e] * 256 + 128 + fl);
            m0 = fminf(m0, __uint_as_float(v << 16));
            m1 = fminf(m1, __uint_as_float(v & 0xffff0000u));
        }
        outv = (__float_as_uint(m0) >> 16) | (__float_as_uint(m1) & 0xffff0000u);
    }
    *(u32*)(Acat + (size_t)node * 256 + fl) = outv;
}

__global__ __launch_bounds__(256) void gather_min3_k(
    const float* __restrict__ feat, const int* __restrict__ ptr,
    const int* __restrict__ csr, float* __restrict__ agg, int n) {
    int i = blockIdx.x * 256 + threadIdx.x;
    if (i >= n) return;
    int e = ptr[i], end = ptr[i + 1];
    bool empty = (e == end);
    float m0 = FLTMAX, m1 = FLTMAX, m2 = FLTMAX;
    for (; e < end; e++) {
        const float* r = feat + (size_t)csr[e] * 3;
        m0 = fminf(m0, r[0]);
        m1 = fminf(m1, r[1]);
        m2 = fminf(m2, r[2]);
    }
    agg[(size_t)i * 3 + 0] = empty ? 0.f : m0;
    agg[(size_t)i * 3 + 1] = empty ? 0.f : m1;
    agg[(size_t)i * 3 + 2] = empty ? 0.f : m2;
}

// ====== convert bn_relu(h) (D=128) -> bf16 into A_cat right half ======
__global__ __launch_bounds__(256) void convert_k(
    const float* __restrict__ h, const float* __restrict__ coef,
    u16* __restrict__ Acat, int n) {
    int t = blockIdx.x * 256 + threadIdx.x;
    int total = n * 32;
    if (t >= total) return;
    int i = t >> 5;
    int dq = (t & 31) * 4;
    const float4 hv = *(const float4*)(h + (size_t)i * 128 + dq);
    const float4 ca = *(const float4*)(coef + dq);
    const float4 cb = *(const float4*)(coef + 128 + dq);
    ushort4 o;
    o.x = f2bf(trf(hv.x, ca.x, cb.x));
    o.y = f2bf(trf(hv.y, ca.y, cb.y));
    o.z = f2bf(trf(hv.z, ca.z, cb.z));
    o.w = f2bf(trf(hv.w, ca.w, cb.w));
    *(ushort4*)(Acat + (size_t)i * 256 + 128 + dq) = o;
}

// ====== weight prep: WT[c][k] = bf16( k<128 ? wl[k][c] : wr[k-128][c] ) ======
__global__ __launch_bounds__(256) void wprep_k(
    const float* __restrict__ wl, const float* __restrict__ wr,
    u16* __restrict__ WT, int N) {
    int t = blockIdx.x * 256 + threadIdx.x;
    if (t >= N * 256) return;
    int c = t >> 8;
    int k = t & 255;
    float v = (k < 128) ? wl[k * N + c] : wr[(k - 128) * N + c];
    WT[(size_t)c * 256 + k] = f2bf(v);
}

// ====== bf16 MFMA GEMM: out[n][128] = A_cat[n][256] @ W_cat[256][128] + bias ======
__global__ __launch_bounds__(256) void gemm_bf_k(
    const u16* __restrict__ A, const u16* __restrict__ WT,
    const float* __restrict__ bl1, const float* __restrict__ bl2,
    float* __restrict__ out, int n) {
    constexpr int NT = 8;
    const int tid = threadIdx.x;
    const int wave = tid >> 6, lane = tid & 63;
    const int quad = lane >> 4, l16 = lane & 15;
    const int row0 = blockIdx.x * 64 + wave * 16;
    const int rowA = min(row0 + l16, n - 1);
    const uint4* Arow = (const uint4*)(A + (size_t)rowA * 256) + quad;

    bf16x8 a[8];
#pragma unroll
    for (int kc = 0; kc < 8; kc++) {
        U16x8 u; u.u = Arow[kc * 4];
        a[kc] = u.b;
    }
    f32x4 acc[NT];
#pragma unroll
    for (int i = 0; i < NT; i++) acc[i] = (f32x4){0.f, 0.f, 0.f, 0.f};
#pragma unroll
    for (int nt = 0; nt < NT; nt++) {
        const uint4* Brow = (const uint4*)(WT + (size_t)(nt * 16 + l16) * 256) + quad;
#pragma unroll
        for (int kc = 0; kc < 8; kc++) {
            U16x8 u; u.u = Brow[kc * 4];
            acc[nt] = __builtin_amdgcn_mfma_f32_16x16x32_bf16(a[kc], u.b, acc[nt], 0, 0, 0);
        }
    }
#pragma unroll
    for (int nt = 0; nt < NT; nt++) {
        const int col = nt * 16 + l16;
        const float bias = (col < 64) ? bl1[col] : bl2[col - 64];
#pragma unroll
        for (int r = 0; r < 4; r++) {
            const int row = row0 + quad * 4 + r;
            if (row < n) out[(size_t)row * 128 + col] = acc[nt][r] + bias;
        }
    }
}

// ====== fp32 linear (layer-1, K=32 -> 128) ======
__global__ __launch_bounds__(256) void linear1_k(
    const float* __restrict__ agg, const float* __restrict__ h,
    const float* __restrict__ wl, const float* __restrict__ bl,
    const float* __restrict__ wr, float* __restrict__ out, int n) {
    constexpr int DOUT = 128, CT = 32, RB = 32;
    const int ct = threadIdx.x % CT;
    const int rt = threadIdx.x / CT;
    const int col = ct * 4;
    const int row0 = blockIdx.x * RB + rt * 4;
    int r_idx[4];
#pragma unroll
    for (int r = 0; r < 4; r++) r_idx[r] = min(row0 + r, n - 1);
    float4 acc[4] = {};
#pragma unroll 2
    for (int k0 = 0; k0 < 32; k0 += 4) {
        float4 wlv[4], wrv[4];
#pragma unroll
        for (int j = 0; j < 4; j++) {
            wlv[j] = *(const float4*)(wl + (size_t)(k0 + j) * DOUT + col);
            wrv[j] = *(const float4*)(wr + (size_t)(k0 + j) * DOUT + col);
        }
#pragma unroll
        for (int r = 0; r < 4; r++) {
            const float4 av = *(const float4*)(agg + (size_t)r_idx[r] * 32 + k0);
            const float4 hv = *(const float4*)(h + (size_t)r_idx[r] * 32 + k0);
#pragma unroll
            for (int j = 0; j < 4; j++) {
                const float aa = j == 0 ? av.x : j == 1 ? av.y : j == 2 ? av.z : av.w;
                const float bb = j == 0 ? hv.x : j == 1 ? hv.y : j == 2 ? hv.z : hv.w;
                acc[r].x += aa * wlv[j].x + bb * wrv[j].x;
                acc[r].y += aa * wlv[j].y + bb * wrv[j].y;
                acc[r].z += aa * wlv[j].z + bb * wrv[j].z;
                acc[r].w += aa * wlv[j].w + bb * wrv[j].w;
            }
        }
    }
    const float4 bv = *(const float4*)(bl + col);
#pragma unroll
    for (int r = 0; r < 4; r++) {
        if (row0 + r < n) {
            float4 o = acc[r];
            o.x += bv.x; o.y += bv.y; o.z += bv.z; o.w += bv.w;
            *(float4*)(out + (size_t)(row0 + r) * DOUT + col) = o;
        }
    }
}

// ====== fp32 linear (layer-2, K=128 -> 64) with fused BN+ReLU on h; 8 rows/thread ======
__global__ __launch_bounds__(256) void linear2_k(
    const float* __restrict__ agg, const float* __restrict__ h,
    const float* __restrict__ coef, const float* __restrict__ wl,
    const float* __restrict__ bl, const float* __restrict__ wr,
    float* __restrict__ out, int n) {
    constexpr int DIN = 128, DOUT = 64, CT = 16, RPT = 8, RB = 128;
    __shared__ float cA[DIN], cB[DIN];
    const int tid = threadIdx.x;
    for (int u = tid; u < DIN; u += 256) { cA[u] = coef[u]; cB[u] = coef[DIN + u]; }
    __syncthreads();
    const int ct = tid % CT;
    const int rt = tid / CT;
    const int col = ct * 4;
    const int row0 = blockIdx.x * RB + rt * RPT;
    int r_idx[RPT];
#pragma unroll
    for (int r = 0; r < RPT; r++) r_idx[r] = min(row0 + r, n - 1);
    float4 acc[RPT] = {};
    for (int k0 = 0; k0 < DIN; k0 += 4) {
        float4 wlv[4], wrv[4];
#pragma unroll
        for (int j = 0; j < 4; j++) {
            wlv[j] = *(const float4*)(wl + (size_t)(k0 + j) * DOUT + col);
            wrv[j] = *(const float4*)(wr + (size_t)(k0 + j) * DOUT + col);
        }
        const float ca0 = cA[k0], ca1 = cA[k0 + 1], ca2 = cA[k0 + 2], ca3 = cA[k0 + 3];
        const float cb0 = cB[k0], cb1 = cB[k0 + 1], cb2 = cB[k0 + 2], cb3 = cB[k0 + 3];
#pragma unroll
        for (int r = 0; r < RPT; r++) {
            const float4 av = *(const float4*)(agg + (size_t)r_idx[r] * DIN + k0);
            float4 hv = *(const float4*)(h + (size_t)r_idx[r] * DIN + k0);
            hv.x = trf(hv.x, ca0, cb0); hv.y = trf(hv.y, ca1, cb1);
            hv.z = trf(hv.z, ca2, cb2); hv.w = trf(hv.w, ca3, cb3);
#pragma unroll
            for (int j = 0; j < 4; j++) {
                const float aa = j == 0 ? av.x : j == 1 ? av.y : j == 2 ? av.z : av.w;
                const float bb = j == 0 ? hv.x : j == 1 ? hv.y : j == 2 ? hv.z : hv.w;
                acc[r].x += aa * wlv[j].x + bb * wrv[j].x;
                acc[r].y += aa * wlv[j].y + bb * wrv[j].y;
                acc[r].z += aa * wlv[j].z + bb * wrv[j].z;
                acc[r].w += aa * wlv[j].w + bb * wrv[j].w;
            }
        }
    }
    const float4 bv = *(const float4*)(bl + col);
#pragma unroll
    for (int r = 0; r < RPT; r++) {
        if (row0 + r < n) {
            float4 o = acc[r];
            o.x += bv.x; o.y += bv.y; o.z += bv.z; o.w += bv.w;
            *(float4*)(out + (size_t)(row0 + r) * DOUT + col) = o;
        }
    }
}

// ====== sh1 linear: concat([x(32), rm(3)]) -> 128, raw operands ======
__global__ __launch_bounds__(256) void linear_sh4_k(
    const float* __restrict__ aggx, const float* __restrict__ x,
    const float* __restrict__ aggr, const float* __restrict__ rm,
    const float* __restrict__ wl, const float* __restrict__ bl,
    const float* __restrict__ wr, float* __restrict__ out, int n) {
    constexpr int DOUT = 128, CT = 32, RB = 32;
    const int ct = threadIdx.x % CT;
    const int rt = threadIdx.x / CT;
    const int col = ct * 4;
    const int row0 = blockIdx.x * RB + rt * 4;
    int r_idx[4];
#pragma unroll
    for (int r = 0; r < 4; r++) r_idx[r] = min(row0 + r, n - 1);
    float4 acc[4] = {};
#pragma unroll 2
    for (int k0 = 0; k0 < 32; k0 += 4) {
        float4 wlv[4], wrv[4];
#pragma unroll
        for (int j = 0; j < 4; j++) {
            wlv[j] = *(const float4*)(wl + (size_t)(k0 + j) * DOUT + col);
            wrv[j] = *(const float4*)(wr + (size_t)(k0 + j) * DOUT + col);
        }
#pragma unroll
        for (int r = 0; r < 4; r++) {
            const float4 av = *(const float4*)(aggx + (size_t)r_idx[r] * 32 + k0);
            const float4 hv = *(const float4*)(x + (size_t)r_idx[r] * 32 + k0);
#pragma unroll
            for (int j = 0; j < 4; j++) {
                const float aa = j == 0 ? av.x : j == 1 ? av.y : j == 2 ? av.z : av.w;
                const float bb = j == 0 ? hv.x : j == 1 ? hv.y : j == 2 ? hv.z : hv.w;
                acc[r].x += aa * wlv[j].x + bb * wrv[j].x;
                acc[r].y += aa * wlv[j].y + bb * wrv[j].y;
                acc[r].z += aa * wlv[j].z + bb * wrv[j].z;
                acc[r].w += aa * wlv[j].w + bb * wrv[j].w;
            }
        }
    }
#pragma unroll
    for (int k = 0; k < 3; k++) {
        const float4 wlv = *(const float4*)(wl + (size_t)(32 + k) * DOUT + col);
        const float4 wrv = *(const float4*)(wr + (size_t)(32 + k) * DOUT + col);
#pragma unroll
        for (int r = 0; r < 4; r++) {
            const float a = aggr[(size_t)r_idx[r] * 3 + k];
            const float b = rm[(size_t)r_idx[r] * 3 + k];
            acc[r].x += a * wlv.x + b * wrv.x;
            acc[r].y += a * wlv.y + b * wrv.y;
            acc[r].z += a * wlv.z + b * wrv.z;
            acc[r].w += a * wlv.w + b * wrv.w;
        }
    }
    const float4 bv = *(const float4*)(bl + col);
#pragma unroll
    for (int r = 0; r < 4; r++) {
        if (row0 + r < n) {
            float4 o = acc[r];
            o.x += bv.x; o.y += bv.y; o.z += bv.z; o.w += bv.w;
            *(float4*)(out + (size_t)(row0 + r) * DOUT + col) = o;
        }
    }
}

// ---- per-column sum / sumsq with LDS pre-reduction ----
template <int D>
__global__ __launch_bounds__(256) void colstats_k(
    const float* __restrict__ x, float* __restrict__ stats, int total) {
    __shared__ float ls[256];
    int t0 = blockIdx.x * 256 + threadIdx.x;
    int stride = gridDim.x * 256;
    float s = 0.f, s2 = 0.f;
    for (int t = t0; t < total; t += stride) {
        float v = x[t];
        s += v;
        s2 += v * v;
    }
    int col = threadIdx.x % D;
    ls[threadIdx.x] = s;
    __syncthreads();
    if (threadIdx.x < D) {
        float a = s;
        for (int u = threadIdx.x + D; u < 256; u += D) a += ls[u];
        atomicAdd(&stats[col], a);
    }
    __syncthreads();
    ls[threadIdx.x] = s2;
    __syncthreads();
    if (threadIdx.x < D) {
        float a = s2;
        for (int u = threadIdx.x + D; u < 256; u += D) a += ls[u];
        atomicAdd(&stats[D + col], a);
    }
}

// ====== per-layer BN coefficients ======
template <int D>
__global__ void coef_k(const float* __restrict__ stats, const float* __restrict__ g,
                       const float* __restrict__ bb, float* __restrict__ coef,
                       float invN) {
    int d = threadIdx.x;
    if (d >= D) return;
    float mu = stats[d] * invN;
    float var = stats[D + d] * invN - mu * mu;
    float a = rsqrtf(var + 1e-5f) * g[d];
    coef[d] = a;
    coef[D + d] = bb[d] - mu * a;
}

__global__ void coef_dual_k(const float* __restrict__ stats,
                            const float* __restrict__ gR, const float* __restrict__ bR,
                            const float* __restrict__ gM, const float* __restrict__ bM,
                            float* __restrict__ coefR, float* __restrict__ coefM,
                            float invN) {
    int d = threadIdx.x;
    if (d >= 128) return;
    float mu = stats[d] * invN;
    float var = stats[128 + d] * invN - mu * mu;
    bool isR = d < 64;
    int c = isR ? d : d - 64;
    float g = isR ? gR[c] : gM[c];
    float be = isR ? bR[c] : bM[c];
    float a = rsqrtf(var + 1e-5f) * g;
    float* co = isR ? coefR : coefM;
    co[c] = a;
    co[64 + c] = be - mu * a;
}

// ====== rm head fused: gather(h2,D=64) + 64->3 linear + log_softmax + labels ======
__global__ __launch_bounds__(256) void rm_fused_k(
    const float* __restrict__ h2, const float* __restrict__ coef,
    const int* __restrict__ ptr, const int* __restrict__ csr,
    const float* __restrict__ wl, const float* __restrict__ bl,
    const float* __restrict__ wr, float* __restrict__ rmb,
    float* __restrict__ ls_out, float* __restrict__ lab, int n) {
    const int lane = threadIdx.x & 63;
    const int node = (blockIdx.x * 256 + threadIdx.x) >> 6;
    if (node >= n) return;
    const float a = coef[lane], b = coef[64 + lane];
    int e = ptr[node];
    const int end = ptr[node + 1];
    const bool empty = (e == end);
    float m = FLTMAX;
    for (; e + 7 < end; e += 8) {
        int s[8];
#pragma unroll
        for (int j = 0; j < 8; j++) s[j] = csr[e + j];
        float v[8];
#pragma unroll
        for (int j = 0; j < 8; j++) v[j] = h2[(size_t)s[j] * 64 + lane];
#pragma unroll
        for (int j = 0; j < 8; j++) m = fminf(m, trf(v[j], a, b));
    }
    for (; e < end; e++) m = fminf(m, trf(h2[(size_t)csr[e] * 64 + lane], a, b));
    m = empty ? 0.f : m;
    const float hv = trf(h2[(size_t)node * 64 + lane], a, b);
    float c0 = m * wl[lane * 3 + 0] + hv * wr[lane * 3 + 0];
    float c1 = m * wl[lane * 3 + 1] + hv * wr[lane * 3 + 1];
    float c2 = m * wl[lane * 3 + 2] + hv * wr[lane * 3 + 2];
#pragma unroll
    for (int off = 1; off < 64; off <<= 1) {
        c0 += __shfl_xor(c0, off);
        c1 += __shfl_xor(c1, off);
        c2 += __shfl_xor(c2, off);
    }
    const float r0 = c0 + bl[0], r1 = c1 + bl[1], r2 = c2 + bl[2];
    if (lane < 3) {
        const float r = lane == 0 ? r0 : lane == 1 ? r1 : r2;
        rmb[(size_t)node * 3 + lane] = r;
        const float mx = fmaxf(r0, fmaxf(r1, r2));
        const float lse = mx + logf(expf(r0 - mx) + expf(r1 - mx) + expf(r2 - mx));
        ls_out[(size_t)node * 3 + lane] = r - lse;
        if (lane == 0) lab[node] = (r2 > r0 && r2 > r1) ? 1.f : 0.f;
    }
}

// ====== final heads: rtmd[n][128] (rt|md) with fused BN+ReLU ======
__global__ __launch_bounds__(256) void final_k(
    const float* __restrict__ rtmd,
    const float* __restrict__ cR, const float* __restrict__ cM,
    const float* __restrict__ rtw, const float* __restrict__ rtb,
    const float* __restrict__ mdw, const float* __restrict__ mdb,
    const float* __restrict__ lab, float* __restrict__ out_rt,
    float* __restrict__ out_md, int n) {
    int i = blockIdx.x * 256 + threadIdx.x;
    if (i >= n) return;
    const float* rr = rtmd + (size_t)i * 128;
    const float* mr = rr + 64;
    float a = rtb[0], b = mdb[0];
#pragma unroll 8
    for (int k = 0; k < 64; k++) {
        a += trf(rr[k], cR[k], cR[64 + k]) * rtw[k];
        b += trf(mr[k], cM[k], cM[64 + k]) * mdw[k];
    }
    float l = lab[i];
    out_rt[i] = a * l;
    out_md[i] = b * l;
}

extern "C" void kernel_launch(void* const* d_in, const int* in_sizes, int n_in,
                              void* d_out, int out_size, void* d_ws, size_t ws_size,
                              hipStream_t stream) {
    const float* x = (const float*)d_in[0];
    const int* ei = (const int*)d_in[1];
    const int E = in_sizes[1] / 2;
    const int n = in_sizes[0] / 32;
    const int* src = ei;
    const int* dst = ei + E;

    const float* rm1_wl = (const float*)d_in[2];
    const float* rm1_bl = (const float*)d_in[3];
    const float* rm1_wr = (const float*)d_in[4];
    const float* rmn1_g = (const float*)d_in[5];
    const float* rmn1_b = (const float*)d_in[6];
    const float* rm2_wl = (const float*)d_in[7];
    const float* rm2_bl = (const float*)d_in[8];
    const float* rm2_wr = (const float*)d_in[9];
    const float* rmn2_g = (const float*)d_in[10];
    const float* rmn2_b = (const float*)d_in[11];
    const float* rm4_wl = (const float*)d_in[12];
    const float* rm4_bl = (const float*)d_in[13];
    const float* rm4_wr = (const float*)d_in[14];
    const float* sh1_wl = (const float*)d_in[15];
    const float* sh1_bl = (const float*)d_in[16];
    const float* sh1_wr = (const float*)d_in[17];
    const float* shn1_g = (const float*)d_in[18];
    const float* shn1_b = (const float*)d_in[19];
    const float* rt1_wl = (const float*)d_in[20];
    const float* rt1_bl = (const float*)d_in[21];
    const float* rt1_wr = (const float*)d_in[22];
    const float* rtn1_g = (const float*)d_in[23];
    const float* rtn1_b = (const float*)d_in[24];
    const float* rt3_w = (const float*)d_in[25];
    const float* rt3_b = (const float*)d_in[26];
    const float* md1_wl = (const float*)d_in[27];
    const float* md1_bl = (const float*)d_in[28];
    const float* md1_wr = (const float*)d_in[29];
    const float* mdn1_g = (const float*)d_in[30];
    const float* mdn1_b = (const float*)d_in[31];
    const float* md3_w = (const float*)d_in[32];
    const float* md3_b = (const float*)d_in[33];

    // workspace layout; shbuf serves as fp32 aggB (layer 2), then bf16 Acat (dual)
    char* w = (char*)d_ws;
    float* aggX  = (float*)w; w += (size_t)n * 32 * 4;
    float* h1    = (float*)w; w += (size_t)n * 128 * 4;   // h1 raw, later h3 raw
    char*  shbuf = w;         w += (size_t)n * 512;       // aggB fp32 [n][128] | Acat bf16 [n][256]
    float* h2rt  = (float*)w; w += (size_t)n * 128 * 4;   // h2 [n][64], later rtmd [n][128]
    float* rmb   = (float*)w; w += (size_t)n * 3 * 4;
    float* aggR  = (float*)w; w += (size_t)n * 3 * 4;
    float* lab   = (float*)w; w += (size_t)n * 4;
    float* stats = (float*)w; w += 1024 * 4;
    float* coef  = (float*)w; w += 1024 * 4;
    u16*   WTD   = (u16*)w;   w += (size_t)128 * 256 * 2;
    int* ptr  = (int*)w; w += (size_t)(n + 1) * 4;
    int* pos  = (int*)w; w += (size_t)n * 4;
    int* bsum = (int*)w; w += 1024 * 4;
    int* csr  = (int*)w; w += (size_t)E * 4;

    float* aggB = (float*)shbuf;
    u16*   Acat = (u16*)shbuf;
    float* h2 = h2rt;
    float* rtmd = h2rt;
    float* stats1 = stats, *stats2 = stats + 256, *statsSh = stats + 512, *statsD = stats + 768;
    float* coef1 = coef, *coef2 = coef + 256, *coefSh = coef + 384;
    float* coefRt = coef + 640, *coefMd = coef + 768;

    float* out = (float*)d_out;
    float* out_ls = out;
    float* out_rt = out + (size_t)3 * n;
    float* out_md = out + (size_t)4 * n;

    const float invN = 1.f / (float)n;
    auto cdiv = [](int a, int b) { return (a + b - 1) / b; };
    const int nb = cdiv(n, 256);

    hipMemsetAsync(stats, 0, 1024 * 4, stream);
    hipMemsetAsync(pos, 0, (size_t)n * 4, stream);

    // ---- CSR build + dual-weight prep (feature-independent)
    hist_k<<<cdiv(E, 256), 256, 0, stream>>>(dst, pos, E);
    wprep_k<<<64, 256, 0, stream>>>(rt1_wl, rt1_wr, WTD, 64);
    wprep_k<<<64, 256, 0, stream>>>(md1_wl, md1_wr, WTD + (size_t)64 * 256, 64);
    scan_block_k<<<nb, 256, 0, stream>>>(pos, ptr, bsum, n);
    scan_bsum_k<<<1, 512, 0, stream>>>(bsum, nb);
    scan_add_k<<<nb, 256, 0, stream>>>(ptr, pos, bsum, n, E);
    csr_fill_k<<<cdiv(E, 256), 256, 0, stream>>>(src, dst, pos, csr, E);

    // ---- layer 1 (fp32): agg(x) -> linear -> h1; stats -> coef1
    gather_min32_k<<<cdiv(n, 8), 256, 0, stream>>>(x, ptr, csr, aggX, n);
    linear1_k<<<cdiv(n, 32), 256, 0, stream>>>(aggX, x, rm1_wl, rm1_bl, rm1_wr, h1, n);
    colstats_k<128><<<256, 256, 0, stream>>>(h1, stats1, n * 128);
    coef_k<128><<<1, 128, 0, stream>>>(stats1, rmn1_g, rmn1_b, coef1, invN);

    // ---- layer 2 (fp32, label-critical): gather(bnrelu(h1)) -> linear -> h2
    gather_min128_k<<<cdiv(n, 4), 256, 0, stream>>>(h1, ptr, csr, coef1, aggB, n);
    linear2_k<<<cdiv(n, 128), 256, 0, stream>>>(aggB, h1, coef1, rm2_wl, rm2_bl, rm2_wr, h2, n);
    colstats_k<64><<<256, 256, 0, stream>>>(h2, stats2, n * 64);
    coef_k<64><<<1, 64, 0, stream>>>(stats2, rmn2_g, rmn2_b, coef2, invN);

    // ---- rm head (fp32): fused gather + linear + log_softmax + labels
    rm_fused_k<<<cdiv(n, 4), 256, 0, stream>>>(h2, coef2, ptr, csr, rm4_wl, rm4_bl, rm4_wr, rmb, out_ls, lab, n);

    // ---- sh1 (fp32): agg(rm); linear concat([x,rm]) -> h3 (h1 buf); stats -> coefSh
    gather_min3_k<<<cdiv(n, 256), 256, 0, stream>>>(rmb, ptr, csr, aggR, n);
    linear_sh4_k<<<cdiv(n, 32), 256, 0, stream>>>(aggX, x, aggR, rmb, sh1_wl, sh1_bl, sh1_wr, h1, n);
    colstats_k<128><<<256, 256, 0, stream>>>(h1, statsSh, n * 128);
    coef_k<128><<<1, 128, 0, stream>>>(statsSh, shn1_g, shn1_b, coefSh, invN);

    // ---- dual rt/md (bf16 MFMA, continuous path):
    convert_k<<<cdiv(n * 32, 256), 256, 0, stream>>>(h1, coefSh, Acat, n);
    gather_bf_k<<<cdiv(n, 4), 256, 0, stream>>>(Acat, ptr, csr, n);
    gemm_bf_k<<<cdiv(n, 64), 256, 0, stream>>>(Acat, WTD, rt1_bl, md1_bl, rtmd, n);
    colstats_k<128><<<256, 256, 0, stream>>>(rtmd, statsD, n * 128);
    coef_dual_k<<<1, 128, 0, stream>>>(statsD, rtn1_g, rtn1_b, mdn1_g, mdn1_b, coefRt, coefMd, invN);

    // ---- final heads
    final_k<<<cdiv(n, 256), 256, 0, stream>>>(rtmd, coefRt, coefMd,
                                              rt3_w, rt3_b, md3_w, md3_b, lab,
                                              out_rt, out_md, n);
}

// Round 9
// 1105.964 us; speedup vs baseline: 1.2028x; 1.2028x over previous
//
#include <hip/hip_runtime.h>

#define FLTMAX 3.402823466e+38f
#define DEV __device__ __forceinline__

typedef unsigned short u16;
typedef unsigned int u32;
typedef __bf16 bf16_t;
typedef bf16_t bf16x8 __attribute__((ext_vector_type(8)));
typedef float f32x4 __attribute__((ext_vector_type(4)));

union U16x8 { uint4 u; bf16x8 b; };

DEV float trf(float v, float a, float b) { return fmaxf(fmaf(v, a, b), 0.f); }

// round-to-nearest-even fp32 -> bf16 bits (finite inputs)
DEV u16 f2bf(float f) {
    u32 u = __float_as_uint(f);
    return (u16)((u + 0x7FFFu + ((u >> 16) & 1u)) >> 16);
}

// ================= CSR build =================
__global__ __launch_bounds__(256) void hist_k(const int* __restrict__ dst,
                                              int* __restrict__ deg, int E) {
    int e = blockIdx.x * 256 + threadIdx.x;
    if (e >= E) return;
    atomicAdd(&deg[dst[e]], 1);
}

__global__ __launch_bounds__(256) void scan_block_k(const int* __restrict__ deg,
                                                    int* __restrict__ ptr,
                                                    int* __restrict__ bsum, int n) {
    __shared__ int ls[256];
    int i = blockIdx.x * 256 + threadIdx.x;
    int v = (i < n) ? deg[i] : 0;
    ls[threadIdx.x] = v;
    __syncthreads();
#pragma unroll
    for (int off = 1; off < 256; off <<= 1) {
        int a = (threadIdx.x >= off) ? ls[threadIdx.x - off] : 0;
        __syncthreads();
        ls[threadIdx.x] += a;
        __syncthreads();
    }
    if (i < n) ptr[i] = ls[threadIdx.x] - v;
    if (threadIdx.x == 255) bsum[blockIdx.x] = ls[255];
}

__global__ __launch_bounds__(512) void scan_bsum_k(int* __restrict__ bsum, int nb) {
    __shared__ int ls[512];
    int t = threadIdx.x;
    int v = (t < nb) ? bsum[t] : 0;
    ls[t] = v;
    __syncthreads();
#pragma unroll
    for (int off = 1; off < 512; off <<= 1) {
        int a = (t >= off) ? ls[t - off] : 0;
        __syncthreads();
        ls[t] += a;
        __syncthreads();
    }
    if (t < nb) bsum[t] = ls[t] - v;
}

__global__ __launch_bounds__(256) void scan_add_k(int* __restrict__ ptr,
                                                  int* __restrict__ pos,
                                                  const int* __restrict__ bsum,
                                                  int n, int E) {
    int i = blockIdx.x * 256 + threadIdx.x;
    if (i == 0) ptr[n] = E;
    if (i < n) {
        int p = ptr[i] + bsum[blockIdx.x];
        ptr[i] = p;
        pos[i] = p;
    }
}

__global__ __launch_bounds__(256) void csr_fill_k(const int* __restrict__ src,
                                                  const int* __restrict__ dst,
                                                  int* __restrict__ pos,
                                                  int* __restrict__ csr, int E) {
    int e = blockIdx.x * 256 + threadIdx.x;
    if (e >= E) return;
    int p = atomicAdd(&pos[dst[e]], 1);
    csr[p] = src[e];
}

// ====== fp32 gather min (layer-1 x, D=32) ======
__global__ __launch_bounds__(256) void gather_min32_k(
    const float* __restrict__ feat, const int* __restrict__ ptr,
    const int* __restrict__ csr, float* __restrict__ agg, int n) {
    const int lane = threadIdx.x & 63;
    const int wave = (blockIdx.x * 256 + threadIdx.x) >> 6;
    const int node = wave * 2 + (lane >> 5);
    if (node >= n) return;
    const int fl = lane & 31;
    int e = ptr[node];
    const int end = ptr[node + 1];
    const bool empty = (e == end);
    float m = FLTMAX;
    for (; e + 3 < end; e += 4) {
        float v0 = feat[(size_t)csr[e] * 32 + fl];
        float v1 = feat[(size_t)csr[e + 1] * 32 + fl];
        float v2 = feat[(size_t)csr[e + 2] * 32 + fl];
        float v3 = feat[(size_t)csr[e + 3] * 32 + fl];
        m = fminf(m, fminf(fminf(v0, v1), fminf(v2, v3)));
    }
    for (; e < end; e++) m = fminf(m, feat[(size_t)csr[e] * 32 + fl]);
    agg[(size_t)node * 32 + fl] = empty ? 0.f : m;
}

// ====== fp32 gather min D=128 with fused BN+ReLU, 8 rows in flight ======
__global__ __launch_bounds__(256) void gather_min128_k(
    const float* __restrict__ feat, const int* __restrict__ ptr,
    const int* __restrict__ csr, const float* __restrict__ coef,
    float* __restrict__ agg, int n) {
    const int lane = threadIdx.x & 63;
    const int node = (blockIdx.x * 256 + threadIdx.x) >> 6;
    if (node >= n) return;
    const int fl = lane * 2;
    const float ca0 = coef[fl], ca1 = coef[fl + 1];
    const float cb0 = coef[128 + fl], cb1 = coef[128 + fl + 1];
    int e = ptr[node];
    const int end = ptr[node + 1];
    const bool empty = (e == end);
    float m0 = FLTMAX, m1 = FLTMAX;
    for (; e + 7 < end; e += 8) {
        int s[8];
#pragma unroll
        for (int j = 0; j < 8; j++) s[j] = csr[e + j];
        float2 v[8];
#pragma unroll
        for (int j = 0; j < 8; j++) v[j] = *(const float2*)(feat + (size_t)s[j] * 128 + fl);
#pragma unroll
        for (int j = 0; j < 8; j++) {
            m0 = fminf(m0, trf(v[j].x, ca0, cb0));
            m1 = fminf(m1, trf(v[j].y, ca1, cb1));
        }
    }
    for (; e + 3 < end; e += 4) {
        const float2 v0 = *(const float2*)(feat + (size_t)csr[e] * 128 + fl);
        const float2 v1 = *(const float2*)(feat + (size_t)csr[e + 1] * 128 + fl);
        const float2 v2 = *(const float2*)(feat + (size_t)csr[e + 2] * 128 + fl);
        const float2 v3 = *(const float2*)(feat + (size_t)csr[e + 3] * 128 + fl);
        m0 = fminf(m0, fminf(fminf(trf(v0.x, ca0, cb0), trf(v1.x, ca0, cb0)),
                             fminf(trf(v2.x, ca0, cb0), trf(v3.x, ca0, cb0))));
        m1 = fminf(m1, fminf(fminf(trf(v0.y, ca1, cb1), trf(v1.y, ca1, cb1)),
                             fminf(trf(v2.y, ca1, cb1), trf(v3.y, ca1, cb1))));
    }
    for (; e < end; e++) {
        const float2 v = *(const float2*)(feat + (size_t)csr[e] * 128 + fl);
        m0 = fminf(m0, trf(v.x, ca0, cb0));
        m1 = fminf(m1, trf(v.y, ca1, cb1));
    }
    float2 o;
    o.x = empty ? 0.f : m0;
    o.y = empty ? 0.f : m1;
    *(float2*)(agg + (size_t)node * 128 + fl) = o;
}

// ====== bf16 gather min over A_cat right half -> left half, 8 rows in flight ======
__global__ __launch_bounds__(256) void gather_bf_k(
    u16* __restrict__ Acat, const int* __restrict__ ptr,
    const int* __restrict__ csr, int n) {
    const int lane = threadIdx.x & 63;
    const int node = (blockIdx.x * 256 + threadIdx.x) >> 6;
    if (node >= n) return;
    const int fl = lane * 2;
    int e = ptr[node];
    const int end = ptr[node + 1];
    u32 outv = 0;
    if (e != end) {
        float m0 = FLTMAX, m1 = FLTMAX;
        for (; e + 7 < end; e += 8) {
            int s[8];
#pragma unroll
            for (int j = 0; j < 8; j++) s[j] = csr[e + j];
            u32 v[8];
#pragma unroll
            for (int j = 0; j < 8; j++) v[j] = *(const u32*)(Acat + (size_t)s[j] * 256 + 128 + fl);
#pragma unroll
            for (int j = 0; j < 8; j++) {
                m0 = fminf(m0, __uint_as_float(v[j] << 16));
                m1 = fminf(m1, __uint_as_float(v[j] & 0xffff0000u));
            }
        }
        for (; e < end; e++) {
            u32 v = *(const u32*)(Acat + (size_t)csr[e] * 256 + 128 + fl);
            m0 = fminf(m0, __uint_as_float(v << 16));
            m1 = fminf(m1, __uint_as_float(v & 0xffff0000u));
        }
        outv = (__float_as_uint(m0) >> 16) | (__float_as_uint(m1) & 0xffff0000u);
    }
    *(u32*)(Acat + (size_t)node * 256 + fl) = outv;
}

__global__ __launch_bounds__(256) void gather_min3_k(
    const float* __restrict__ feat, const int* __restrict__ ptr,
    const int* __restrict__ csr, float* __restrict__ agg, int n) {
    int i = blockIdx.x * 256 + threadIdx.x;
    if (i >= n) return;
    int e = ptr[i], end = ptr[i + 1];
    bool empty = (e == end);
    float m0 = FLTMAX, m1 = FLTMAX, m2 = FLTMAX;
    for (; e < end; e++) {
        const float* r = feat + (size_t)csr[e] * 3;
        m0 = fminf(m0, r[0]);
        m1 = fminf(m1, r[1]);
        m2 = fminf(m2, r[2]);
    }
    agg[(size_t)i * 3 + 0] = empty ? 0.f : m0;
    agg[(size_t)i * 3 + 1] = empty ? 0.f : m1;
    agg[(size_t)i * 3 + 2] = empty ? 0.f : m2;
}

// ====== convert bn_relu(h) (D=128) -> bf16 into A_cat right half ======
__global__ __launch_bounds__(256) void convert_k(
    const float* __restrict__ h, const float* __restrict__ coef,
    u16* __restrict__ Acat, int n) {
    int t = blockIdx.x * 256 + threadIdx.x;
    int total = n * 32;
    if (t >= total) return;
    int i = t >> 5;
    int dq = (t & 31) * 4;
    const float4 hv = *(const float4*)(h + (size_t)i * 128 + dq);
    const float4 ca = *(const float4*)(coef + dq);
    const float4 cb = *(const float4*)(coef + 128 + dq);
    ushort4 o;
    o.x = f2bf(trf(hv.x, ca.x, cb.x));
    o.y = f2bf(trf(hv.y, ca.y, cb.y));
    o.z = f2bf(trf(hv.z, ca.z, cb.z));
    o.w = f2bf(trf(hv.w, ca.w, cb.w));
    *(ushort4*)(Acat + (size_t)i * 256 + 128 + dq) = o;
}

// ====== weight prep: WT[c][k] = bf16( k<128 ? wl[k][c] : wr[k-128][c] ) ======
__global__ __launch_bounds__(256) void wprep_k(
    const float* __restrict__ wl, const float* __restrict__ wr,
    u16* __restrict__ WT, int N) {
    int t = blockIdx.x * 256 + threadIdx.x;
    if (t >= N * 256) return;
    int c = t >> 8;
    int k = t & 255;
    float v = (k < 128) ? wl[k * N + c] : wr[(k - 128) * N + c];
    WT[(size_t)c * 256 + k] = f2bf(v);
}

// ====== bf16 MFMA GEMM: out[n][128] = A_cat[n][256] @ W_cat[256][128] + bias ======
__global__ __launch_bounds__(256) void gemm_bf_k(
    const u16* __restrict__ A, const u16* __restrict__ WT,
    const float* __restrict__ bl1, const float* __restrict__ bl2,
    float* __restrict__ out, int n) {
    constexpr int NT = 8;
    const int tid = threadIdx.x;
    const int wave = tid >> 6, lane = tid & 63;
    const int quad = lane >> 4, l16 = lane & 15;
    const int row0 = blockIdx.x * 64 + wave * 16;
    const int rowA = min(row0 + l16, n - 1);
    const uint4* Arow = (const uint4*)(A + (size_t)rowA * 256) + quad;

    bf16x8 a[8];
#pragma unroll
    for (int kc = 0; kc < 8; kc++) {
        U16x8 u; u.u = Arow[kc * 4];
        a[kc] = u.b;
    }
    f32x4 acc[NT];
#pragma unroll
    for (int i = 0; i < NT; i++) acc[i] = (f32x4){0.f, 0.f, 0.f, 0.f};
#pragma unroll
    for (int nt = 0; nt < NT; nt++) {
        const uint4* Brow = (const uint4*)(WT + (size_t)(nt * 16 + l16) * 256) + quad;
#pragma unroll
        for (int kc = 0; kc < 8; kc++) {
            U16x8 u; u.u = Brow[kc * 4];
            acc[nt] = __builtin_amdgcn_mfma_f32_16x16x32_bf16(a[kc], u.b, acc[nt], 0, 0, 0);
        }
    }
#pragma unroll
    for (int nt = 0; nt < NT; nt++) {
        const int col = nt * 16 + l16;
        const float bias = (col < 64) ? bl1[col] : bl2[col - 64];
#pragma unroll
        for (int r = 0; r < 4; r++) {
            const int row = row0 + quad * 4 + r;
            if (row < n) out[(size_t)row * 128 + col] = acc[nt][r] + bias;
        }
    }
}

// ====== fp32 linear (layer-1, K=32 -> 128) ======
__global__ __launch_bounds__(256) void linear1_k(
    const float* __restrict__ agg, const float* __restrict__ h,
    const float* __restrict__ wl, const float* __restrict__ bl,
    const float* __restrict__ wr, float* __restrict__ out, int n) {
    constexpr int DOUT = 128, CT = 32, RB = 32;
    const int ct = threadIdx.x % CT;
    const int rt = threadIdx.x / CT;
    const int col = ct * 4;
    const int row0 = blockIdx.x * RB + rt * 4;
    int r_idx[4];
#pragma unroll
    for (int r = 0; r < 4; r++) r_idx[r] = min(row0 + r, n - 1);
    float4 acc[4] = {};
#pragma unroll 2
    for (int k0 = 0; k0 < 32; k0 += 4) {
        float4 wlv[4], wrv[4];
#pragma unroll
        for (int j = 0; j < 4; j++) {
            wlv[j] = *(const float4*)(wl + (size_t)(k0 + j) * DOUT + col);
            wrv[j] = *(const float4*)(wr + (size_t)(k0 + j) * DOUT + col);
        }
#pragma unroll
        for (int r = 0; r < 4; r++) {
            const float4 av = *(const float4*)(agg + (size_t)r_idx[r] * 32 + k0);
            const float4 hv = *(const float4*)(h + (size_t)r_idx[r] * 32 + k0);
#pragma unroll
            for (int j = 0; j < 4; j++) {
                const float aa = j == 0 ? av.x : j == 1 ? av.y : j == 2 ? av.z : av.w;
                const float bb = j == 0 ? hv.x : j == 1 ? hv.y : j == 2 ? hv.z : hv.w;
                acc[r].x += aa * wlv[j].x + bb * wrv[j].x;
                acc[r].y += aa * wlv[j].y + bb * wrv[j].y;
                acc[r].z += aa * wlv[j].z + bb * wrv[j].z;
                acc[r].w += aa * wlv[j].w + bb * wrv[j].w;
            }
        }
    }
    const float4 bv = *(const float4*)(bl + col);
#pragma unroll
    for (int r = 0; r < 4; r++) {
        if (row0 + r < n) {
            float4 o = acc[r];
            o.x += bv.x; o.y += bv.y; o.z += bv.z; o.w += bv.w;
            *(float4*)(out + (size_t)(row0 + r) * DOUT + col) = o;
        }
    }
}

// ====== fp32 linear (layer-2, K=128 -> 64), LDS-staged A/h tiles ======
// Numerics bit-identical to the R6 version: trf applied once at staging,
// FMA accumulation order unchanged (k ascending, j ascending).
__global__ __launch_bounds__(256) void linear2_k(
    const float* __restrict__ agg, const float* __restrict__ h,
    const float* __restrict__ coef, const float* __restrict__ wl,
    const float* __restrict__ bl, const float* __restrict__ wr,
    float* __restrict__ out, int n) {
    constexpr int DIN = 128, DOUT = 64, CT = 16, RB = 64, LDW = 132;
    __shared__ float Ash[RB * LDW];   // 33.8 KB
    __shared__ float Hsh[RB * LDW];   // 33.8 KB
    const int tid = threadIdx.x;
    const int base = blockIdx.x * RB;
    // ---- stage: thread t covers row t>>2, 8 float4 chunks (col4 = (t&3)+4c)
    {
        const int sr = tid >> 2;
        const int sc = tid & 3;
        const int grow = min(base + sr, n - 1);
        const float* ar = agg + (size_t)grow * DIN;
        const float* hr = h + (size_t)grow * DIN;
#pragma unroll
        for (int c = 0; c < 8; c++) {
            const int col = (sc + c * 4) * 4;
            const float4 av = *(const float4*)(ar + col);
            float4 hv = *(const float4*)(hr + col);
            const float4 ca = *(const float4*)(coef + col);
            const float4 cb = *(const float4*)(coef + DIN + col);
            hv.x = trf(hv.x, ca.x, cb.x); hv.y = trf(hv.y, ca.y, cb.y);
            hv.z = trf(hv.z, ca.z, cb.z); hv.w = trf(hv.w, ca.w, cb.w);
            *(float4*)(Ash + sr * LDW + col) = av;
            *(float4*)(Hsh + sr * LDW + col) = hv;
        }
    }
    __syncthreads();
    // ---- compute: 4 rows x 4 cols per thread; A/h from LDS, weights global
    const int ct = tid % CT;
    const int rt = tid / CT;
    const int col = ct * 4;
    const int row0 = base + rt * 4;
    float4 acc[4] = {};
#pragma unroll 2
    for (int k0 = 0; k0 < DIN; k0 += 4) {
        float4 wlv[4], wrv[4];
#pragma unroll
        for (int j = 0; j < 4; j++) {
            wlv[j] = *(const float4*)(wl + (size_t)(k0 + j) * DOUT + col);
            wrv[j] = *(const float4*)(wr + (size_t)(k0 + j) * DOUT + col);
        }
#pragma unroll
        for (int r = 0; r < 4; r++) {
            const float4 av = *(const float4*)(Ash + (rt * 4 + r) * LDW + k0);
            const float4 hv = *(const float4*)(Hsh + (rt * 4 + r) * LDW + k0);
#pragma unroll
            for (int j = 0; j < 4; j++) {
                const float aa = j == 0 ? av.x : j == 1 ? av.y : j == 2 ? av.z : av.w;
                const float bb = j == 0 ? hv.x : j == 1 ? hv.y : j == 2 ? hv.z : hv.w;
                acc[r].x += aa * wlv[j].x + bb * wrv[j].x;
                acc[r].y += aa * wlv[j].y + bb * wrv[j].y;
                acc[r].z += aa * wlv[j].z + bb * wrv[j].z;
                acc[r].w += aa * wlv[j].w + bb * wrv[j].w;
            }
        }
    }
    const float4 bv = *(const float4*)(bl + col);
#pragma unroll
    for (int r = 0; r < 4; r++) {
        if (row0 + r < n) {
            float4 o = acc[r];
            o.x += bv.x; o.y += bv.y; o.z += bv.z; o.w += bv.w;
            *(float4*)(out + (size_t)(row0 + r) * DOUT + col) = o;
        }
    }
}

// ====== sh1 linear: concat([x(32), rm(3)]) -> 128, raw operands ======
__global__ __launch_bounds__(256) void linear_sh4_k(
    const float* __restrict__ aggx, const float* __restrict__ x,
    const float* __restrict__ aggr, const float* __restrict__ rm,
    const float* __restrict__ wl, const float* __restrict__ bl,
    const float* __restrict__ wr, float* __restrict__ out, int n) {
    constexpr int DOUT = 128, CT = 32, RB = 32;
    const int ct = threadIdx.x % CT;
    const int rt = threadIdx.x / CT;
    const int col = ct * 4;
    const int row0 = blockIdx.x * RB + rt * 4;
    int r_idx[4];
#pragma unroll
    for (int r = 0; r < 4; r++) r_idx[r] = min(row0 + r, n - 1);
    float4 acc[4] = {};
#pragma unroll 2
    for (int k0 = 0; k0 < 32; k0 += 4) {
        float4 wlv[4], wrv[4];
#pragma unroll
        for (int j = 0; j < 4; j++) {
            wlv[j] = *(const float4*)(wl + (size_t)(k0 + j) * DOUT + col);
            wrv[j] = *(const float4*)(wr + (size_t)(k0 + j) * DOUT + col);
        }
#pragma unroll
        for (int r = 0; r < 4; r++) {
            const float4 av = *(const float4*)(aggx + (size_t)r_idx[r] * 32 + k0);
            const float4 hv = *(const float4*)(x + (size_t)r_idx[r] * 32 + k0);
#pragma unroll
            for (int j = 0; j < 4; j++) {
                const float aa = j == 0 ? av.x : j == 1 ? av.y : j == 2 ? av.z : av.w;
                const float bb = j == 0 ? hv.x : j == 1 ? hv.y : j == 2 ? hv.z : hv.w;
                acc[r].x += aa * wlv[j].x + bb * wrv[j].x;
                acc[r].y += aa * wlv[j].y + bb * wrv[j].y;
                acc[r].z += aa * wlv[j].z + bb * wrv[j].z;
                acc[r].w += aa * wlv[j].w + bb * wrv[j].w;
            }
        }
    }
#pragma unroll
    for (int k = 0; k < 3; k++) {
        const float4 wlv = *(const float4*)(wl + (size_t)(32 + k) * DOUT + col);
        const float4 wrv = *(const float4*)(wr + (size_t)(32 + k) * DOUT + col);
#pragma unroll
        for (int r = 0; r < 4; r++) {
            const float a = aggr[(size_t)r_idx[r] * 3 + k];
            const float b = rm[(size_t)r_idx[r] * 3 + k];
            acc[r].x += a * wlv.x + b * wrv.x;
            acc[r].y += a * wlv.y + b * wrv.y;
            acc[r].z += a * wlv.z + b * wrv.z;
            acc[r].w += a * wlv.w + b * wrv.w;
        }
    }
    const float4 bv = *(const float4*)(bl + col);
#pragma unroll
    for (int r = 0; r < 4; r++) {
        if (row0 + r < n) {
            float4 o = acc[r];
            o.x += bv.x; o.y += bv.y; o.z += bv.z; o.w += bv.w;
            *(float4*)(out + (size_t)(row0 + r) * DOUT + col) = o;
        }
    }
}

// ---- per-column sum / sumsq with LDS pre-reduction ----
template <int D>
__global__ __launch_bounds__(256) void colstats_k(
    const float* __restrict__ x, float* __restrict__ stats, int total) {
    __shared__ float ls[256];
    int t0 = blockIdx.x * 256 + threadIdx.x;
    int stride = gridDim.x * 256;
    float s = 0.f, s2 = 0.f;
    for (int t = t0; t < total; t += stride) {
        float v = x[t];
        s += v;
        s2 += v * v;
    }
    int col = threadIdx.x % D;
    ls[threadIdx.x] = s;
    __syncthreads();
    if (threadIdx.x < D) {
        float a = s;
        for (int u = threadIdx.x + D; u < 256; u += D) a += ls[u];
        atomicAdd(&stats[col], a);
    }
    __syncthreads();
    ls[threadIdx.x] = s2;
    __syncthreads();
    if (threadIdx.x < D) {
        float a = s2;
        for (int u = threadIdx.x + D; u < 256; u += D) a += ls[u];
        atomicAdd(&stats[D + col], a);
    }
}

// ====== per-layer BN coefficients ======
template <int D>
__global__ void coef_k(const float* __restrict__ stats, const float* __restrict__ g,
                       const float* __restrict__ bb, float* __restrict__ coef,
                       float invN) {
    int d = threadIdx.x;
    if (d >= D) return;
    float mu = stats[d] * invN;
    float var = stats[D + d] * invN - mu * mu;
    float a = rsqrtf(var + 1e-5f) * g[d];
    coef[d] = a;
    coef[D + d] = bb[d] - mu * a;
}

__global__ void coef_dual_k(const float* __restrict__ stats,
                            const float* __restrict__ gR, const float* __restrict__ bR,
                            const float* __restrict__ gM, const float* __restrict__ bM,
                            float* __restrict__ coefR, float* __restrict__ coefM,
                            float invN) {
    int d = threadIdx.x;
    if (d >= 128) return;
    float mu = stats[d] * invN;
    float var = stats[128 + d] * invN - mu * mu;
    bool isR = d < 64;
    int c = isR ? d : d - 64;
    float g = isR ? gR[c] : gM[c];
    float be = isR ? bR[c] : bM[c];
    float a = rsqrtf(var + 1e-5f) * g;
    float* co = isR ? coefR : coefM;
    co[c] = a;
    co[64 + c] = be - mu * a;
}

// ====== rm head fused: gather(h2,D=64) + 64->3 linear + log_softmax + labels ======
__global__ __launch_bounds__(256) void rm_fused_k(
    const float* __restrict__ h2, const float* __restrict__ coef,
    const int* __restrict__ ptr, const int* __restrict__ csr,
    const float* __restrict__ wl, const float* __restrict__ bl,
    const float* __restrict__ wr, float* __restrict__ rmb,
    float* __restrict__ ls_out, float* __restrict__ lab, int n) {
    const int lane = threadIdx.x & 63;
    const int node = (blockIdx.x * 256 + threadIdx.x) >> 6;
    if (node >= n) return;
    const float a = coef[lane], b = coef[64 + lane];
    int e = ptr[node];
    const int end = ptr[node + 1];
    const bool empty = (e == end);
    float m = FLTMAX;
    for (; e + 7 < end; e += 8) {
        int s[8];
#pragma unroll
        for (int j = 0; j < 8; j++) s[j] = csr[e + j];
        float v[8];
#pragma unroll
        for (int j = 0; j < 8; j++) v[j] = h2[(size_t)s[j] * 64 + lane];
#pragma unroll
        for (int j = 0; j < 8; j++) m = fminf(m, trf(v[j], a, b));
    }
    for (; e < end; e++) m = fminf(m, trf(h2[(size_t)csr[e] * 64 + lane], a, b));
    m = empty ? 0.f : m;
    const float hv = trf(h2[(size_t)node * 64 + lane], a, b);
    float c0 = m * wl[lane * 3 + 0] + hv * wr[lane * 3 + 0];
    float c1 = m * wl[lane * 3 + 1] + hv * wr[lane * 3 + 1];
    float c2 = m * wl[lane * 3 + 2] + hv * wr[lane * 3 + 2];
#pragma unroll
    for (int off = 1; off < 64; off <<= 1) {
        c0 += __shfl_xor(c0, off);
        c1 += __shfl_xor(c1, off);
        c2 += __shfl_xor(c2, off);
    }
    const float r0 = c0 + bl[0], r1 = c1 + bl[1], r2 = c2 + bl[2];
    if (lane < 3) {
        const float r = lane == 0 ? r0 : lane == 1 ? r1 : r2;
        rmb[(size_t)node * 3 + lane] = r;
        const float mx = fmaxf(r0, fmaxf(r1, r2));
        const float lse = mx + logf(expf(r0 - mx) + expf(r1 - mx) + expf(r2 - mx));
        ls_out[(size_t)node * 3 + lane] = r - lse;
        if (lane == 0) lab[node] = (r2 > r0 && r2 > r1) ? 1.f : 0.f;
    }
}

// ====== final heads: rtmd[n][128] (rt|md) with fused BN+ReLU ======
__global__ __launch_bounds__(256) void final_k(
    const float* __restrict__ rtmd,
    const float* __restrict__ cR, const float* __restrict__ cM,
    const float* __restrict__ rtw, const float* __restrict__ rtb,
    const float* __restrict__ mdw, const float* __restrict__ mdb,
    const float* __restrict__ lab, float* __restrict__ out_rt,
    float* __restrict__ out_md, int n) {
    int i = blockIdx.x * 256 + threadIdx.x;
    if (i >= n) return;
    const float* rr = rtmd + (size_t)i * 128;
    const float* mr = rr + 64;
    float a = rtb[0], b = mdb[0];
#pragma unroll 8
    for (int k = 0; k < 64; k++) {
        a += trf(rr[k], cR[k], cR[64 + k]) * rtw[k];
        b += trf(mr[k], cM[k], cM[64 + k]) * mdw[k];
    }
    float l = lab[i];
    out_rt[i] = a * l;
    out_md[i] = b * l;
}

extern "C" void kernel_launch(void* const* d_in, const int* in_sizes, int n_in,
                              void* d_out, int out_size, void* d_ws, size_t ws_size,
                              hipStream_t stream) {
    const float* x = (const float*)d_in[0];
    const int* ei = (const int*)d_in[1];
    const int E = in_sizes[1] / 2;
    const int n = in_sizes[0] / 32;
    const int* src = ei;
    const int* dst = ei + E;

    const float* rm1_wl = (const float*)d_in[2];
    const float* rm1_bl = (const float*)d_in[3];
    const float* rm1_wr = (const float*)d_in[4];
    const float* rmn1_g = (const float*)d_in[5];
    const float* rmn1_b = (const float*)d_in[6];
    const float* rm2_wl = (const float*)d_in[7];
    const float* rm2_bl = (const float*)d_in[8];
    const float* rm2_wr = (const float*)d_in[9];
    const float* rmn2_g = (const float*)d_in[10];
    const float* rmn2_b = (const float*)d_in[11];
    const float* rm4_wl = (const float*)d_in[12];
    const float* rm4_bl = (const float*)d_in[13];
    const float* rm4_wr = (const float*)d_in[14];
    const float* sh1_wl = (const float*)d_in[15];
    const float* sh1_bl = (const float*)d_in[16];
    const float* sh1_wr = (const float*)d_in[17];
    const float* shn1_g = (const float*)d_in[18];
    const float* shn1_b = (const float*)d_in[19];
    const float* rt1_wl = (const float*)d_in[20];
    const float* rt1_bl = (const float*)d_in[21];
    const float* rt1_wr = (const float*)d_in[22];
    const float* rtn1_g = (const float*)d_in[23];
    const float* rtn1_b = (const float*)d_in[24];
    const float* rt3_w = (const float*)d_in[25];
    const float* rt3_b = (const float*)d_in[26];
    const float* md1_wl = (const float*)d_in[27];
    const float* md1_bl = (const float*)d_in[28];
    const float* md1_wr = (const float*)d_in[29];
    const float* mdn1_g = (const float*)d_in[30];
    const float* mdn1_b = (const float*)d_in[31];
    const float* md3_w = (const float*)d_in[32];
    const float* md3_b = (const float*)d_in[33];

    // workspace layout; shbuf serves as fp32 aggB (layer 2), then bf16 Acat (dual)
    char* w = (char*)d_ws;
    float* aggX  = (float*)w; w += (size_t)n * 32 * 4;
    float* h1    = (float*)w; w += (size_t)n * 128 * 4;   // h1 raw, later h3 raw
    char*  shbuf = w;         w += (size_t)n * 512;       // aggB fp32 [n][128] | Acat bf16 [n][256]
    float* h2rt  = (float*)w; w += (size_t)n * 128 * 4;   // h2 [n][64], later rtmd [n][128]
    float* rmb   = (float*)w; w += (size_t)n * 3 * 4;
    float* aggR  = (float*)w; w += (size_t)n * 3 * 4;
    float* lab   = (float*)w; w += (size_t)n * 4;
    float* stats = (float*)w; w += 1024 * 4;
    float* coef  = (float*)w; w += 1024 * 4;
    u16*   WTD   = (u16*)w;   w += (size_t)128 * 256 * 2;
    int* ptr  = (int*)w; w += (size_t)(n + 1) * 4;
    int* pos  = (int*)w; w += (size_t)n * 4;
    int* bsum = (int*)w; w += 1024 * 4;
    int* csr  = (int*)w; w += (size_t)E * 4;

    float* aggB = (float*)shbuf;
    u16*   Acat = (u16*)shbuf;
    float* h2 = h2rt;
    float* rtmd = h2rt;
    float* stats1 = stats, *stats2 = stats + 256, *statsSh = stats + 512, *statsD = stats + 768;
    float* coef1 = coef, *coef2 = coef + 256, *coefSh = coef + 384;
    float* coefRt = coef + 640, *coefMd = coef + 768;

    float* out = (float*)d_out;
    float* out_ls = out;
    float* out_rt = out + (size_t)3 * n;
    float* out_md = out + (size_t)4 * n;

    const float invN = 1.f / (float)n;
    auto cdiv = [](int a, int b) { return (a + b - 1) / b; };
    const int nb = cdiv(n, 256);

    hipMemsetAsync(stats, 0, 1024 * 4, stream);
    hipMemsetAsync(pos, 0, (size_t)n * 4, stream);

    // ---- CSR build + dual-weight prep (feature-independent)
    hist_k<<<cdiv(E, 256), 256, 0, stream>>>(dst, pos, E);
    wprep_k<<<64, 256, 0, stream>>>(rt1_wl, rt1_wr, WTD, 64);
    wprep_k<<<64, 256, 0, stream>>>(md1_wl, md1_wr, WTD + (size_t)64 * 256, 64);
    scan_block_k<<<nb, 256, 0, stream>>>(pos, ptr, bsum, n);
    scan_bsum_k<<<1, 512, 0, stream>>>(bsum, nb);
    scan_add_k<<<nb, 256, 0, stream>>>(ptr, pos, bsum, n, E);
    csr_fill_k<<<cdiv(E, 256), 256, 0, stream>>>(src, dst, pos, csr, E);

    // ---- layer 1 (fp32): agg(x) -> linear -> h1; stats -> coef1
    gather_min32_k<<<cdiv(n, 8), 256, 0, stream>>>(x, ptr, csr, aggX, n);
    linear1_k<<<cdiv(n, 32), 256, 0, stream>>>(aggX, x, rm1_wl, rm1_bl, rm1_wr, h1, n);
    colstats_k<128><<<256, 256, 0, stream>>>(h1, stats1, n * 128);
    coef_k<128><<<1, 128, 0, stream>>>(stats1, rmn1_g, rmn1_b, coef1, invN);

    // ---- layer 2 (fp32, label-critical): gather(bnrelu(h1)) -> linear -> h2
    gather_min128_k<<<cdiv(n, 4), 256, 0, stream>>>(h1, ptr, csr, coef1, aggB, n);
    linear2_k<<<cdiv(n, 64), 256, 0, stream>>>(aggB, h1, coef1, rm2_wl, rm2_bl, rm2_wr, h2, n);
    colstats_k<64><<<256, 256, 0, stream>>>(h2, stats2, n * 64);
    coef_k<64><<<1, 64, 0, stream>>>(stats2, rmn2_g, rmn2_b, coef2, invN);

    // ---- rm head (fp32): fused gather + linear + log_softmax + labels
    rm_fused_k<<<cdiv(n, 4), 256, 0, stream>>>(h2, coef2, ptr, csr, rm4_wl, rm4_bl, rm4_wr, rmb, out_ls, lab, n);

    // ---- sh1 (fp32): agg(rm); linear concat([x,rm]) -> h3 (h1 buf); stats -> coefSh
    gather_min3_k<<<cdiv(n, 256), 256, 0, stream>>>(rmb, ptr, csr, aggR, n);
    linear_sh4_k<<<cdiv(n, 32), 256, 0, stream>>>(aggX, x, aggR, rmb, sh1_wl, sh1_bl, sh1_wr, h1, n);
    colstats_k<128><<<256, 256, 0, stream>>>(h1, statsSh, n * 128);
    coef_k<128><<<1, 128, 0, stream>>>(statsSh, shn1_g, shn1_b, coefSh, invN);

    // ---- dual rt/md (bf16 MFMA, continuous path):
    convert_k<<<cdiv(n * 32, 256), 256, 0, stream>>>(h1, coefSh, Acat, n);
    gather_bf_k<<<cdiv(n, 4), 256, 0, stream>>>(Acat, ptr, csr, n);
    gemm_bf_k<<<cdiv(n, 64), 256, 0, stream>>>(Acat, WTD, rt1_bl, md1_bl, rtmd, n);
    colstats_k<128><<<256, 256, 0, stream>>>(rtmd, statsD, n * 128);
    coef_dual_k<<<1, 128, 0, stream>>>(statsD, rtn1_g, rtn1_b, mdn1_g, mdn1_b, coefRt, coefMd, invN);

    // ---- final heads
    final_k<<<cdiv(n, 256), 256, 0, stream>>>(rtmd, coefRt, coefMd,
                                              rt3_w, rt3_b, md3_w, md3_b, lab,
                                              out_rt, out_md, n);
}

// Round 10
// 1053.137 us; speedup vs baseline: 1.2631x; 1.0502x over previous
//
#include <hip/hip_runtime.h>

#define FLTMAX 3.402823466e+38f
#define DEV __device__ __forceinline__

typedef unsigned short u16;
typedef unsigned int u32;
typedef __bf16 bf16_t;
typedef bf16_t bf16x8 __attribute__((ext_vector_type(8)));
typedef float f32x4 __attribute__((ext_vector_type(4)));

union U16x8 { uint4 u; bf16x8 b; };

DEV float trf(float v, float a, float b) { return fmaxf(fmaf(v, a, b), 0.f); }

// round-to-nearest-even fp32 -> bf16 bits (finite inputs)
DEV u16 f2bf(float f) {
    u32 u = __float_as_uint(f);
    return (u16)((u + 0x7FFFu + ((u >> 16) & 1u)) >> 16);
}

// ================= CSR build =================
__global__ __launch_bounds__(256) void hist_k(const int* __restrict__ dst,
                                              int* __restrict__ deg, int E) {
    int e = blockIdx.x * 256 + threadIdx.x;
    if (e >= E) return;
    atomicAdd(&deg[dst[e]], 1);
}

__global__ __launch_bounds__(256) void scan_block_k(const int* __restrict__ deg,
                                                    int* __restrict__ ptr,
                                                    int* __restrict__ bsum, int n) {
    __shared__ int ls[256];
    int i = blockIdx.x * 256 + threadIdx.x;
    int v = (i < n) ? deg[i] : 0;
    ls[threadIdx.x] = v;
    __syncthreads();
#pragma unroll
    for (int off = 1; off < 256; off <<= 1) {
        int a = (threadIdx.x >= off) ? ls[threadIdx.x - off] : 0;
        __syncthreads();
        ls[threadIdx.x] += a;
        __syncthreads();
    }
    if (i < n) ptr[i] = ls[threadIdx.x] - v;
    if (threadIdx.x == 255) bsum[blockIdx.x] = ls[255];
}

__global__ __launch_bounds__(512) void scan_bsum_k(int* __restrict__ bsum, int nb) {
    __shared__ int ls[512];
    int t = threadIdx.x;
    int v = (t < nb) ? bsum[t] : 0;
    ls[t] = v;
    __syncthreads();
#pragma unroll
    for (int off = 1; off < 512; off <<= 1) {
        int a = (t >= off) ? ls[t - off] : 0;
        __syncthreads();
        ls[t] += a;
        __syncthreads();
    }
    if (t < nb) bsum[t] = ls[t] - v;
}

__global__ __launch_bounds__(256) void scan_add_k(int* __restrict__ ptr,
                                                  int* __restrict__ pos,
                                                  const int* __restrict__ bsum,
                                                  int n, int E) {
    int i = blockIdx.x * 256 + threadIdx.x;
    if (i == 0) ptr[n] = E;
    if (i < n) {
        int p = ptr[i] + bsum[blockIdx.x];
        ptr[i] = p;
        pos[i] = p;
    }
}

// XCD-partitioned fill: block b handles dst-partition (b&7), edge chunk (b>>3).
// All writes to a given csr bucket (and its pos counter) issue from blocks of
// one partition => one XCD under round-robin mapping => L2-merged, single evict.
// Within-bucket order changes vs serial fill; min-aggregation is order-invariant.
__global__ __launch_bounds__(256) void csr_fill_part_k(
    const int* __restrict__ src, const int* __restrict__ dst,
    int* __restrict__ pos, int* __restrict__ csr, int E, int lo_step) {
    const int part = blockIdx.x & 7;
    const int e = (blockIdx.x >> 3) * 256 + threadIdx.x;
    if (e >= E) return;
    const int d = dst[e];
    const int lo = part * lo_step;
    const int hi = lo + lo_step;       // last partition's hi covers n (lo_step = cdiv(n,8))
    if (d < lo || d >= hi) return;
    const int p = atomicAdd(&pos[d], 1);
    csr[p] = src[e];
}

// ====== fp32 gather min (layer-1 x, D=32) ======
__global__ __launch_bounds__(256) void gather_min32_k(
    const float* __restrict__ feat, const int* __restrict__ ptr,
    const int* __restrict__ csr, float* __restrict__ agg, int n) {
    const int lane = threadIdx.x & 63;
    const int wave = (blockIdx.x * 256 + threadIdx.x) >> 6;
    const int node = wave * 2 + (lane >> 5);
    if (node >= n) return;
    const int fl = lane & 31;
    int e = ptr[node];
    const int end = ptr[node + 1];
    const bool empty = (e == end);
    float m = FLTMAX;
    for (; e + 3 < end; e += 4) {
        float v0 = feat[(size_t)csr[e] * 32 + fl];
        float v1 = feat[(size_t)csr[e + 1] * 32 + fl];
        float v2 = feat[(size_t)csr[e + 2] * 32 + fl];
        float v3 = feat[(size_t)csr[e + 3] * 32 + fl];
        m = fminf(m, fminf(fminf(v0, v1), fminf(v2, v3)));
    }
    for (; e < end; e++) m = fminf(m, feat[(size_t)csr[e] * 32 + fl]);
    agg[(size_t)node * 32 + fl] = empty ? 0.f : m;
}

// ====== fp32 gather min D=128 with fused BN+ReLU, 8 rows in flight ======
__global__ __launch_bounds__(256) void gather_min128_k(
    const float* __restrict__ feat, const int* __restrict__ ptr,
    const int* __restrict__ csr, const float* __restrict__ coef,
    float* __restrict__ agg, int n) {
    const int lane = threadIdx.x & 63;
    const int node = (blockIdx.x * 256 + threadIdx.x) >> 6;
    if (node >= n) return;
    const int fl = lane * 2;
    const float ca0 = coef[fl], ca1 = coef[fl + 1];
    const float cb0 = coef[128 + fl], cb1 = coef[128 + fl + 1];
    int e = ptr[node];
    const int end = ptr[node + 1];
    const bool empty = (e == end);
    float m0 = FLTMAX, m1 = FLTMAX;
    for (; e + 7 < end; e += 8) {
        int s[8];
#pragma unroll
        for (int j = 0; j < 8; j++) s[j] = csr[e + j];
        float2 v[8];
#pragma unroll
        for (int j = 0; j < 8; j++) v[j] = *(const float2*)(feat + (size_t)s[j] * 128 + fl);
#pragma unroll
        for (int j = 0; j < 8; j++) {
            m0 = fminf(m0, trf(v[j].x, ca0, cb0));
            m1 = fminf(m1, trf(v[j].y, ca1, cb1));
        }
    }
    for (; e + 3 < end; e += 4) {
        const float2 v0 = *(const float2*)(feat + (size_t)csr[e] * 128 + fl);
        const float2 v1 = *(const float2*)(feat + (size_t)csr[e + 1] * 128 + fl);
        const float2 v2 = *(const float2*)(feat + (size_t)csr[e + 2] * 128 + fl);
        const float2 v3 = *(const float2*)(feat + (size_t)csr[e + 3] * 128 + fl);
        m0 = fminf(m0, fminf(fminf(trf(v0.x, ca0, cb0), trf(v1.x, ca0, cb0)),
                             fminf(trf(v2.x, ca0, cb0), trf(v3.x, ca0, cb0))));
        m1 = fminf(m1, fminf(fminf(trf(v0.y, ca1, cb1), trf(v1.y, ca1, cb1)),
                             fminf(trf(v2.y, ca1, cb1), trf(v3.y, ca1, cb1))));
    }
    for (; e < end; e++) {
        const float2 v = *(const float2*)(feat + (size_t)csr[e] * 128 + fl);
        m0 = fminf(m0, trf(v.x, ca0, cb0));
        m1 = fminf(m1, trf(v.y, ca1, cb1));
    }
    float2 o;
    o.x = empty ? 0.f : m0;
    o.y = empty ? 0.f : m1;
    *(float2*)(agg + (size_t)node * 128 + fl) = o;
}

// ====== bf16 gather min over A_cat right half -> left half, 8 rows in flight ======
__global__ __launch_bounds__(256) void gather_bf_k(
    u16* __restrict__ Acat, const int* __restrict__ ptr,
    const int* __restrict__ csr, int n) {
    const int lane = threadIdx.x & 63;
    const int node = (blockIdx.x * 256 + threadIdx.x) >> 6;
    if (node >= n) return;
    const int fl = lane * 2;
    int e = ptr[node];
    const int end = ptr[node + 1];
    u32 outv = 0;
    if (e != end) {
        float m0 = FLTMAX, m1 = FLTMAX;
        for (; e + 7 < end; e += 8) {
            int s[8];
#pragma unroll
            for (int j = 0; j < 8; j++) s[j] = csr[e + j];
            u32 v[8];
#pragma unroll
            for (int j = 0; j < 8; j++) v[j] = *(const u32*)(Acat + (size_t)s[j] * 256 + 128 + fl);
#pragma unroll
            for (int j = 0; j < 8; j++) {
                m0 = fminf(m0, __uint_as_float(v[j] << 16));
                m1 = fminf(m1, __uint_as_float(v[j] & 0xffff0000u));
            }
        }
        for (; e < end; e++) {
            u32 v = *(const u32*)(Acat + (size_t)csr[e] * 256 + 128 + fl);
            m0 = fminf(m0, __uint_as_float(v << 16));
            m1 = fminf(m1, __uint_as_float(v & 0xffff0000u));
        }
        outv = (__float_as_uint(m0) >> 16) | (__float_as_uint(m1) & 0xffff0000u);
    }
    *(u32*)(Acat + (size_t)node * 256 + fl) = outv;
}

__global__ __launch_bounds__(256) void gather_min3_k(
    const float* __restrict__ feat, const int* __restrict__ ptr,
    const int* __restrict__ csr, float* __restrict__ agg, int n) {
    int i = blockIdx.x * 256 + threadIdx.x;
    if (i >= n) return;
    int e = ptr[i], end = ptr[i + 1];
    bool empty = (e == end);
    float m0 = FLTMAX, m1 = FLTMAX, m2 = FLTMAX;
    for (; e < end; e++) {
        const float* r = feat + (size_t)csr[e] * 3;
        m0 = fminf(m0, r[0]);
        m1 = fminf(m1, r[1]);
        m2 = fminf(m2, r[2]);
    }
    agg[(size_t)i * 3 + 0] = empty ? 0.f : m0;
    agg[(size_t)i * 3 + 1] = empty ? 0.f : m1;
    agg[(size_t)i * 3 + 2] = empty ? 0.f : m2;
}

// ====== convert bn_relu(h) (D=128) -> bf16 into A_cat right half ======
__global__ __launch_bounds__(256) void convert_k(
    const float* __restrict__ h, const float* __restrict__ coef,
    u16* __restrict__ Acat, int n) {
    int t = blockIdx.x * 256 + threadIdx.x;
    int total = n * 32;
    if (t >= total) return;
    int i = t >> 5;
    int dq = (t & 31) * 4;
    const float4 hv = *(const float4*)(h + (size_t)i * 128 + dq);
    const float4 ca = *(const float4*)(coef + dq);
    const float4 cb = *(const float4*)(coef + 128 + dq);
    ushort4 o;
    o.x = f2bf(trf(hv.x, ca.x, cb.x));
    o.y = f2bf(trf(hv.y, ca.y, cb.y));
    o.z = f2bf(trf(hv.z, ca.z, cb.z));
    o.w = f2bf(trf(hv.w, ca.w, cb.w));
    *(ushort4*)(Acat + (size_t)i * 256 + 128 + dq) = o;
}

// ====== weight prep: WT[c][k] = bf16( k<128 ? wl[k][c] : wr[k-128][c] ) ======
__global__ __launch_bounds__(256) void wprep_k(
    const float* __restrict__ wl, const float* __restrict__ wr,
    u16* __restrict__ WT, int N) {
    int t = blockIdx.x * 256 + threadIdx.x;
    if (t >= N * 256) return;
    int c = t >> 8;
    int k = t & 255;
    float v = (k < 128) ? wl[k * N + c] : wr[(k - 128) * N + c];
    WT[(size_t)c * 256 + k] = f2bf(v);
}

// ====== bf16 MFMA GEMM: out[n][128] = A_cat[n][256] @ W_cat[256][128] + bias ======
__global__ __launch_bounds__(256) void gemm_bf_k(
    const u16* __restrict__ A, const u16* __restrict__ WT,
    const float* __restrict__ bl1, const float* __restrict__ bl2,
    float* __restrict__ out, int n) {
    constexpr int NT = 8;
    const int tid = threadIdx.x;
    const int wave = tid >> 6, lane = tid & 63;
    const int quad = lane >> 4, l16 = lane & 15;
    const int row0 = blockIdx.x * 64 + wave * 16;
    const int rowA = min(row0 + l16, n - 1);
    const uint4* Arow = (const uint4*)(A + (size_t)rowA * 256) + quad;

    bf16x8 a[8];
#pragma unroll
    for (int kc = 0; kc < 8; kc++) {
        U16x8 u; u.u = Arow[kc * 4];
        a[kc] = u.b;
    }
    f32x4 acc[NT];
#pragma unroll
    for (int i = 0; i < NT; i++) acc[i] = (f32x4){0.f, 0.f, 0.f, 0.f};
#pragma unroll
    for (int nt = 0; nt < NT; nt++) {
        const uint4* Brow = (const uint4*)(WT + (size_t)(nt * 16 + l16) * 256) + quad;
#pragma unroll
        for (int kc = 0; kc < 8; kc++) {
            U16x8 u; u.u = Brow[kc * 4];
            acc[nt] = __builtin_amdgcn_mfma_f32_16x16x32_bf16(a[kc], u.b, acc[nt], 0, 0, 0);
        }
    }
#pragma unroll
    for (int nt = 0; nt < NT; nt++) {
        const int col = nt * 16 + l16;
        const float bias = (col < 64) ? bl1[col] : bl2[col - 64];
#pragma unroll
        for (int r = 0; r < 4; r++) {
            const int row = row0 + quad * 4 + r;
            if (row < n) out[(size_t)row * 128 + col] = acc[nt][r] + bias;
        }
    }
}

// ====== fp32 linear (layer-1, K=32 -> 128) ======
__global__ __launch_bounds__(256) void linear1_k(
    const float* __restrict__ agg, const float* __restrict__ h,
    const float* __restrict__ wl, const float* __restrict__ bl,
    const float* __restrict__ wr, float* __restrict__ out, int n) {
    constexpr int DOUT = 128, CT = 32, RB = 32;
    const int ct = threadIdx.x % CT;
    const int rt = threadIdx.x / CT;
    const int col = ct * 4;
    const int row0 = blockIdx.x * RB + rt * 4;
    int r_idx[4];
#pragma unroll
    for (int r = 0; r < 4; r++) r_idx[r] = min(row0 + r, n - 1);
    float4 acc[4] = {};
#pragma unroll 2
    for (int k0 = 0; k0 < 32; k0 += 4) {
        float4 wlv[4], wrv[4];
#pragma unroll
        for (int j = 0; j < 4; j++) {
            wlv[j] = *(const float4*)(wl + (size_t)(k0 + j) * DOUT + col);
            wrv[j] = *(const float4*)(wr + (size_t)(k0 + j) * DOUT + col);
        }
#pragma unroll
        for (int r = 0; r < 4; r++) {
            const float4 av = *(const float4*)(agg + (size_t)r_idx[r] * 32 + k0);
            const float4 hv = *(const float4*)(h + (size_t)r_idx[r] * 32 + k0);
#pragma unroll
            for (int j = 0; j < 4; j++) {
                const float aa = j == 0 ? av.x : j == 1 ? av.y : j == 2 ? av.z : av.w;
                const float bb = j == 0 ? hv.x : j == 1 ? hv.y : j == 2 ? hv.z : hv.w;
                acc[r].x += aa * wlv[j].x + bb * wrv[j].x;
                acc[r].y += aa * wlv[j].y + bb * wrv[j].y;
                acc[r].z += aa * wlv[j].z + bb * wrv[j].z;
                acc[r].w += aa * wlv[j].w + bb * wrv[j].w;
            }
        }
    }
    const float4 bv = *(const float4*)(bl + col);
#pragma unroll
    for (int r = 0; r < 4; r++) {
        if (row0 + r < n) {
            float4 o = acc[r];
            o.x += bv.x; o.y += bv.y; o.z += bv.z; o.w += bv.w;
            *(float4*)(out + (size_t)(row0 + r) * DOUT + col) = o;
        }
    }
}

// ====== fp32 linear (layer-2, K=128 -> 64), LDS-staged A/h tiles ======
__global__ __launch_bounds__(256) void linear2_k(
    const float* __restrict__ agg, const float* __restrict__ h,
    const float* __restrict__ coef, const float* __restrict__ wl,
    const float* __restrict__ bl, const float* __restrict__ wr,
    float* __restrict__ out, int n) {
    constexpr int DIN = 128, DOUT = 64, CT = 16, RB = 64, LDW = 132;
    __shared__ float Ash[RB * LDW];   // 33.8 KB
    __shared__ float Hsh[RB * LDW];   // 33.8 KB
    const int tid = threadIdx.x;
    const int base = blockIdx.x * RB;
    {
        const int sr = tid >> 2;
        const int sc = tid & 3;
        const int grow = min(base + sr, n - 1);
        const float* ar = agg + (size_t)grow * DIN;
        const float* hr = h + (size_t)grow * DIN;
#pragma unroll
        for (int c = 0; c < 8; c++) {
            const int col = (sc + c * 4) * 4;
            const float4 av = *(const float4*)(ar + col);
            float4 hv = *(const float4*)(hr + col);
            const float4 ca = *(const float4*)(coef + col);
            const float4 cb = *(const float4*)(coef + DIN + col);
            hv.x = trf(hv.x, ca.x, cb.x); hv.y = trf(hv.y, ca.y, cb.y);
            hv.z = trf(hv.z, ca.z, cb.z); hv.w = trf(hv.w, ca.w, cb.w);
            *(float4*)(Ash + sr * LDW + col) = av;
            *(float4*)(Hsh + sr * LDW + col) = hv;
        }
    }
    __syncthreads();
    const int ct = tid % CT;
    const int rt = tid / CT;
    const int col = ct * 4;
    const int row0 = base + rt * 4;
    float4 acc[4] = {};
#pragma unroll 2
    for (int k0 = 0; k0 < DIN; k0 += 4) {
        float4 wlv[4], wrv[4];
#pragma unroll
        for (int j = 0; j < 4; j++) {
            wlv[j] = *(const float4*)(wl + (size_t)(k0 + j) * DOUT + col);
            wrv[j] = *(const float4*)(wr + (size_t)(k0 + j) * DOUT + col);
        }
#pragma unroll
        for (int r = 0; r < 4; r++) {
            const float4 av = *(const float4*)(Ash + (rt * 4 + r) * LDW + k0);
            const float4 hv = *(const float4*)(Hsh + (rt * 4 + r) * LDW + k0);
#pragma unroll
            for (int j = 0; j < 4; j++) {
                const float aa = j == 0 ? av.x : j == 1 ? av.y : j == 2 ? av.z : av.w;
                const float bb = j == 0 ? hv.x : j == 1 ? hv.y : j == 2 ? hv.z : hv.w;
                acc[r].x += aa * wlv[j].x + bb * wrv[j].x;
                acc[r].y += aa * wlv[j].y + bb * wrv[j].y;
                acc[r].z += aa * wlv[j].z + bb * wrv[j].z;
                acc[r].w += aa * wlv[j].w + bb * wrv[j].w;
            }
        }
    }
    const float4 bv = *(const float4*)(bl + col);
#pragma unroll
    for (int r = 0; r < 4; r++) {
        if (row0 + r < n) {
            float4 o = acc[r];
            o.x += bv.x; o.y += bv.y; o.z += bv.z; o.w += bv.w;
            *(float4*)(out + (size_t)(row0 + r) * DOUT + col) = o;
        }
    }
}

// ====== sh1 linear: concat([x(32), rm(3)]) -> 128, raw operands ======
__global__ __launch_bounds__(256) void linear_sh4_k(
    const float* __restrict__ aggx, const float* __restrict__ x,
    const float* __restrict__ aggr, const float* __restrict__ rm,
    const float* __restrict__ wl, const float* __restrict__ bl,
    const float* __restrict__ wr, float* __restrict__ out, int n) {
    constexpr int DOUT = 128, CT = 32, RB = 32;
    const int ct = threadIdx.x % CT;
    const int rt = threadIdx.x / CT;
    const int col = ct * 4;
    const int row0 = blockIdx.x * RB + rt * 4;
    int r_idx[4];
#pragma unroll
    for (int r = 0; r < 4; r++) r_idx[r] = min(row0 + r, n - 1);
    float4 acc[4] = {};
#pragma unroll 2
    for (int k0 = 0; k0 < 32; k0 += 4) {
        float4 wlv[4], wrv[4];
#pragma unroll
        for (int j = 0; j < 4; j++) {
            wlv[j] = *(const float4*)(wl + (size_t)(k0 + j) * DOUT + col);
            wrv[j] = *(const float4*)(wr + (size_t)(k0 + j) * DOUT + col);
        }
#pragma unroll
        for (int r = 0; r < 4; r++) {
            const float4 av = *(const float4*)(aggx + (size_t)r_idx[r] * 32 + k0);
            const float4 hv = *(const float4*)(x + (size_t)r_idx[r] * 32 + k0);
#pragma unroll
            for (int j = 0; j < 4; j++) {
                const float aa = j == 0 ? av.x : j == 1 ? av.y : j == 2 ? av.z : av.w;
                const float bb = j == 0 ? hv.x : j == 1 ? hv.y : j == 2 ? hv.z : hv.w;
                acc[r].x += aa * wlv[j].x + bb * wrv[j].x;
                acc[r].y += aa * wlv[j].y + bb * wrv[j].y;
                acc[r].z += aa * wlv[j].z + bb * wrv[j].z;
                acc[r].w += aa * wlv[j].w + bb * wrv[j].w;
            }
        }
    }
#pragma unroll
    for (int k = 0; k < 3; k++) {
        const float4 wlv = *(const float4*)(wl + (size_t)(32 + k) * DOUT + col);
        const float4 wrv = *(const float4*)(wr + (size_t)(32 + k) * DOUT + col);
#pragma unroll
        for (int r = 0; r < 4; r++) {
            const float a = aggr[(size_t)r_idx[r] * 3 + k];
            const float b = rm[(size_t)r_idx[r] * 3 + k];
            acc[r].x += a * wlv.x + b * wrv.x;
            acc[r].y += a * wlv.y + b * wrv.y;
            acc[r].z += a * wlv.z + b * wrv.z;
            acc[r].w += a * wlv.w + b * wrv.w;
        }
    }
    const float4 bv = *(const float4*)(bl + col);
#pragma unroll
    for (int r = 0; r < 4; r++) {
        if (row0 + r < n) {
            float4 o = acc[r];
            o.x += bv.x; o.y += bv.y; o.z += bv.z; o.w += bv.w;
            *(float4*)(out + (size_t)(row0 + r) * DOUT + col) = o;
        }
    }
}

// ---- per-column sum / sumsq with LDS pre-reduction ----
template <int D>
__global__ __launch_bounds__(256) void colstats_k(
    const float* __restrict__ x, float* __restrict__ stats, int total) {
    __shared__ float ls[256];
    int t0 = blockIdx.x * 256 + threadIdx.x;
    int stride = gridDim.x * 256;
    float s = 0.f, s2 = 0.f;
    for (int t = t0; t < total; t += stride) {
        float v = x[t];
        s += v;
        s2 += v * v;
    }
    int col = threadIdx.x % D;
    ls[threadIdx.x] = s;
    __syncthreads();
    if (threadIdx.x < D) {
        float a = s;
        for (int u = threadIdx.x + D; u < 256; u += D) a += ls[u];
        atomicAdd(&stats[col], a);
    }
    __syncthreads();
    ls[threadIdx.x] = s2;
    __syncthreads();
    if (threadIdx.x < D) {
        float a = s2;
        for (int u = threadIdx.x + D; u < 256; u += D) a += ls[u];
        atomicAdd(&stats[D + col], a);
    }
}

// ====== per-layer BN coefficients ======
template <int D>
__global__ void coef_k(const float* __restrict__ stats, const float* __restrict__ g,
                       const float* __restrict__ bb, float* __restrict__ coef,
                       float invN) {
    int d = threadIdx.x;
    if (d >= D) return;
    float mu = stats[d] * invN;
    float var = stats[D + d] * invN - mu * mu;
    float a = rsqrtf(var + 1e-5f) * g[d];
    coef[d] = a;
    coef[D + d] = bb[d] - mu * a;
}

__global__ void coef_dual_k(const float* __restrict__ stats,
                            const float* __restrict__ gR, const float* __restrict__ bR,
                            const float* __restrict__ gM, const float* __restrict__ bM,
                            float* __restrict__ coefR, float* __restrict__ coefM,
                            float invN) {
    int d = threadIdx.x;
    if (d >= 128) return;
    float mu = stats[d] * invN;
    float var = stats[128 + d] * invN - mu * mu;
    bool isR = d < 64;
    int c = isR ? d : d - 64;
    float g = isR ? gR[c] : gM[c];
    float be = isR ? bR[c] : bM[c];
    float a = rsqrtf(var + 1e-5f) * g;
    float* co = isR ? coefR : coefM;
    co[c] = a;
    co[64 + c] = be - mu * a;
}

// ====== rm head fused: gather(h2,D=64) + 64->3 linear + log_softmax + labels ======
__global__ __launch_bounds__(256) void rm_fused_k(
    const float* __restrict__ h2, const float* __restrict__ coef,
    const int* __restrict__ ptr, const int* __restrict__ csr,
    const float* __restrict__ wl, const float* __restrict__ bl,
    const float* __restrict__ wr, float* __restrict__ rmb,
    float* __restrict__ ls_out, float* __restrict__ lab, int n) {
    const int lane = threadIdx.x & 63;
    const int node = (blockIdx.x * 256 + threadIdx.x) >> 6;
    if (node >= n) return;
    const float a = coef[lane], b = coef[64 + lane];
    int e = ptr[node];
    const int end = ptr[node + 1];
    const bool empty = (e == end);
    float m = FLTMAX;
    for (; e + 7 < end; e += 8) {
        int s[8];
#pragma unroll
        for (int j = 0; j < 8; j++) s[j] = csr[e + j];
        float v[8];
#pragma unroll
        for (int j = 0; j < 8; j++) v[j] = h2[(size_t)s[j] * 64 + lane];
#pragma unroll
        for (int j = 0; j < 8; j++) m = fminf(m, trf(v[j], a, b));
    }
    for (; e < end; e++) m = fminf(m, trf(h2[(size_t)csr[e] * 64 + lane], a, b));
    m = empty ? 0.f : m;
    const float hv = trf(h2[(size_t)node * 64 + lane], a, b);
    float c0 = m * wl[lane * 3 + 0] + hv * wr[lane * 3 + 0];
    float c1 = m * wl[lane * 3 + 1] + hv * wr[lane * 3 + 1];
    float c2 = m * wl[lane * 3 + 2] + hv * wr[lane * 3 + 2];
#pragma unroll
    for (int off = 1; off < 64; off <<= 1) {
        c0 += __shfl_xor(c0, off);
        c1 += __shfl_xor(c1, off);
        c2 += __shfl_xor(c2, off);
    }
    const float r0 = c0 + bl[0], r1 = c1 + bl[1], r2 = c2 + bl[2];
    if (lane < 3) {
        const float r = lane == 0 ? r0 : lane == 1 ? r1 : r2;
        rmb[(size_t)node * 3 + lane] = r;
        const float mx = fmaxf(r0, fmaxf(r1, r2));
        const float lse = mx + logf(expf(r0 - mx) + expf(r1 - mx) + expf(r2 - mx));
        ls_out[(size_t)node * 3 + lane] = r - lse;
        if (lane == 0) lab[node] = (r2 > r0 && r2 > r1) ? 1.f : 0.f;
    }
}

// ====== final heads: rtmd[n][128] (rt|md) with fused BN+ReLU ======
__global__ __launch_bounds__(256) void final_k(
    const float* __restrict__ rtmd,
    const float* __restrict__ cR, const float* __restrict__ cM,
    const float* __restrict__ rtw, const float* __restrict__ rtb,
    const float* __restrict__ mdw, const float* __restrict__ mdb,
    const float* __restrict__ lab, float* __restrict__ out_rt,
    float* __restrict__ out_md, int n) {
    int i = blockIdx.x * 256 + threadIdx.x;
    if (i >= n) return;
    const float* rr = rtmd + (size_t)i * 128;
    const float* mr = rr + 64;
    float a = rtb[0], b = mdb[0];
#pragma unroll 8
    for (int k = 0; k < 64; k++) {
        a += trf(rr[k], cR[k], cR[64 + k]) * rtw[k];
        b += trf(mr[k], cM[k], cM[64 + k]) * mdw[k];
    }
    float l = lab[i];
    out_rt[i] = a * l;
    out_md[i] = b * l;
}

extern "C" void kernel_launch(void* const* d_in, const int* in_sizes, int n_in,
                              void* d_out, int out_size, void* d_ws, size_t ws_size,
                              hipStream_t stream) {
    const float* x = (const float*)d_in[0];
    const int* ei = (const int*)d_in[1];
    const int E = in_sizes[1] / 2;
    const int n = in_sizes[0] / 32;
    const int* src = ei;
    const int* dst = ei + E;

    const float* rm1_wl = (const float*)d_in[2];
    const float* rm1_bl = (const float*)d_in[3];
    const float* rm1_wr = (const float*)d_in[4];
    const float* rmn1_g = (const float*)d_in[5];
    const float* rmn1_b = (const float*)d_in[6];
    const float* rm2_wl = (const float*)d_in[7];
    const float* rm2_bl = (const float*)d_in[8];
    const float* rm2_wr = (const float*)d_in[9];
    const float* rmn2_g = (const float*)d_in[10];
    const float* rmn2_b = (const float*)d_in[11];
    const float* rm4_wl = (const float*)d_in[12];
    const float* rm4_bl = (const float*)d_in[13];
    const float* rm4_wr = (const float*)d_in[14];
    const float* sh1_wl = (const float*)d_in[15];
    const float* sh1_bl = (const float*)d_in[16];
    const float* sh1_wr = (const float*)d_in[17];
    const float* shn1_g = (const float*)d_in[18];
    const float* shn1_b = (const float*)d_in[19];
    const float* rt1_wl = (const float*)d_in[20];
    const float* rt1_bl = (const float*)d_in[21];
    const float* rt1_wr = (const float*)d_in[22];
    const float* rtn1_g = (const float*)d_in[23];
    const float* rtn1_b = (const float*)d_in[24];
    const float* rt3_w = (const float*)d_in[25];
    const float* rt3_b = (const float*)d_in[26];
    const float* md1_wl = (const float*)d_in[27];
    const float* md1_bl = (const float*)d_in[28];
    const float* md1_wr = (const float*)d_in[29];
    const float* mdn1_g = (const float*)d_in[30];
    const float* mdn1_b = (const float*)d_in[31];
    const float* md3_w = (const float*)d_in[32];
    const float* md3_b = (const float*)d_in[33];

    // workspace layout; shbuf serves as fp32 aggB (layer 2), then bf16 Acat (dual)
    char* w = (char*)d_ws;
    float* aggX  = (float*)w; w += (size_t)n * 32 * 4;
    float* h1    = (float*)w; w += (size_t)n * 128 * 4;   // h1 raw, later h3 raw
    char*  shbuf = w;         w += (size_t)n * 512;       // aggB fp32 [n][128] | Acat bf16 [n][256]
    float* h2rt  = (float*)w; w += (size_t)n * 128 * 4;   // h2 [n][64], later rtmd [n][128]
    float* rmb   = (float*)w; w += (size_t)n * 3 * 4;
    float* aggR  = (float*)w; w += (size_t)n * 3 * 4;
    float* lab   = (float*)w; w += (size_t)n * 4;
    float* stats = (float*)w; w += 1024 * 4;
    float* coef  = (float*)w; w += 1024 * 4;
    u16*   WTD   = (u16*)w;   w += (size_t)128 * 256 * 2;
    int* ptr  = (int*)w; w += (size_t)(n + 1) * 4;
    int* pos  = (int*)w; w += (size_t)n * 4;
    int* bsum = (int*)w; w += 1024 * 4;
    int* csr  = (int*)w; w += (size_t)E * 4;

    float* aggB = (float*)shbuf;
    u16*   Acat = (u16*)shbuf;
    float* h2 = h2rt;
    float* rtmd = h2rt;
    float* stats1 = stats, *stats2 = stats + 256, *statsSh = stats + 512, *statsD = stats + 768;
    float* coef1 = coef, *coef2 = coef + 256, *coefSh = coef + 384;
    float* coefRt = coef + 640, *coefMd = coef + 768;

    float* out = (float*)d_out;
    float* out_ls = out;
    float* out_rt = out + (size_t)3 * n;
    float* out_md = out + (size_t)4 * n;

    const float invN = 1.f / (float)n;
    auto cdiv = [](int a, int b) { return (a + b - 1) / b; };
    const int nb = cdiv(n, 256);

    hipMemsetAsync(stats, 0, 1024 * 4, stream);
    hipMemsetAsync(pos, 0, (size_t)n * 4, stream);

    // ---- CSR build + dual-weight prep (feature-independent)
    hist_k<<<cdiv(E, 256), 256, 0, stream>>>(dst, pos, E);
    wprep_k<<<64, 256, 0, stream>>>(rt1_wl, rt1_wr, WTD, 64);
    wprep_k<<<64, 256, 0, stream>>>(md1_wl, md1_wr, WTD + (size_t)64 * 256, 64);
    scan_block_k<<<nb, 256, 0, stream>>>(pos, ptr, bsum, n);
    scan_bsum_k<<<1, 512, 0, stream>>>(bsum, nb);
    scan_add_k<<<nb, 256, 0, stream>>>(ptr, pos, bsum, n, E);
    // XCD-partitioned fill: 8x blocks, partition = blockIdx & 7
    csr_fill_part_k<<<cdiv(E, 256) * 8, 256, 0, stream>>>(src, dst, pos, csr, E, cdiv(n, 8));

    // ---- layer 1 (fp32): agg(x) -> linear -> h1; stats -> coef1
    gather_min32_k<<<cdiv(n, 8), 256, 0, stream>>>(x, ptr, csr, aggX, n);
    linear1_k<<<cdiv(n, 32), 256, 0, stream>>>(aggX, x, rm1_wl, rm1_bl, rm1_wr, h1, n);
    colstats_k<128><<<256, 256, 0, stream>>>(h1, stats1, n * 128);
    coef_k<128><<<1, 128, 0, stream>>>(stats1, rmn1_g, rmn1_b, coef1, invN);

    // ---- layer 2 (fp32, label-critical): gather(bnrelu(h1)) -> linear -> h2
    gather_min128_k<<<cdiv(n, 4), 256, 0, stream>>>(h1, ptr, csr, coef1, aggB, n);
    linear2_k<<<cdiv(n, 64), 256, 0, stream>>>(aggB, h1, coef1, rm2_wl, rm2_bl, rm2_wr, h2, n);
    colstats_k<64><<<256, 256, 0, stream>>>(h2, stats2, n * 64);
    coef_k<64><<<1, 64, 0, stream>>>(stats2, rmn2_g, rmn2_b, coef2, invN);

    // ---- rm head (fp32): fused gather + linear + log_softmax + labels
    rm_fused_k<<<cdiv(n, 4), 256, 0, stream>>>(h2, coef2, ptr, csr, rm4_wl, rm4_bl, rm4_wr, rmb, out_ls, lab, n);

    // ---- sh1 (fp32): agg(rm); linear concat([x,rm]) -> h3 (h1 buf); stats -> coefSh
    gather_min3_k<<<cdiv(n, 256), 256, 0, stream>>>(rmb, ptr, csr, aggR, n);
    linear_sh4_k<<<cdiv(n, 32), 256, 0, stream>>>(aggX, x, aggR, rmb, sh1_wl, sh1_bl, sh1_wr, h1, n);
    colstats_k<128><<<256, 256, 0, stream>>>(h1, statsSh, n * 128);
    coef_k<128><<<1, 128, 0, stream>>>(statsSh, shn1_g, shn1_b, coefSh, invN);

    // ---- dual rt/md (bf16 MFMA, continuous path):
    convert_k<<<cdiv(n * 32, 256), 256, 0, stream>>>(h1, coefSh, Acat, n);
    gather_bf_k<<<cdiv(n, 4), 256, 0, stream>>>(Acat, ptr, csr, n);
    gemm_bf_k<<<cdiv(n, 64), 256, 0, stream>>>(Acat, WTD, rt1_bl, md1_bl, rtmd, n);
    colstats_k<128><<<256, 256, 0, stream>>>(rtmd, statsD, n * 128);
    coef_dual_k<<<1, 128, 0, stream>>>(statsD, rtn1_g, rtn1_b, mdn1_g, mdn1_b, coefRt, coefMd, invN);

    // ---- final heads
    final_k<<<cdiv(n, 256), 256, 0, stream>>>(rtmd, coefRt, coefMd,
                                              rt3_w, rt3_b, md3_w, md3_b, lab,
                                              out_rt, out_md, n);
}

// Round 11
// 1032.939 us; speedup vs baseline: 1.2878x; 1.0196x over previous
//
#include <hip/hip_runtime.h>

#define FLTMAX 3.402823466e+38f
#define DEV __device__ __forceinline__

typedef unsigned short u16;
typedef unsigned int u32;
typedef __bf16 bf16_t;
typedef bf16_t bf16x8 __attribute__((ext_vector_type(8)));
typedef float f32x4 __attribute__((ext_vector_type(4)));

union U16x8 { uint4 u; bf16x8 b; };

DEV float trf(float v, float a, float b) { return fmaxf(fmaf(v, a, b), 0.f); }

// round-to-nearest-even fp32 -> bf16 bits (finite inputs)
DEV u16 f2bf(float f) {
    u32 u = __float_as_uint(f);
    return (u16)((u + 0x7FFFu + ((u >> 16) & 1u)) >> 16);
}

// ================= CSR build =================
__global__ __launch_bounds__(256) void hist_k(const int* __restrict__ dst,
                                              int* __restrict__ deg, int E) {
    int e = blockIdx.x * 256 + threadIdx.x;
    if (e >= E) return;
    atomicAdd(&deg[dst[e]], 1);
}

__global__ __launch_bounds__(256) void scan_block_k(const int* __restrict__ deg,
                                                    int* __restrict__ ptr,
                                                    int* __restrict__ bsum, int n) {
    __shared__ int ls[256];
    int i = blockIdx.x * 256 + threadIdx.x;
    int v = (i < n) ? deg[i] : 0;
    ls[threadIdx.x] = v;
    __syncthreads();
#pragma unroll
    for (int off = 1; off < 256; off <<= 1) {
        int a = (threadIdx.x >= off) ? ls[threadIdx.x - off] : 0;
        __syncthreads();
        ls[threadIdx.x] += a;
        __syncthreads();
    }
    if (i < n) ptr[i] = ls[threadIdx.x] - v;
    if (threadIdx.x == 255) bsum[blockIdx.x] = ls[255];
}

__global__ __launch_bounds__(512) void scan_bsum_k(int* __restrict__ bsum, int nb) {
    __shared__ int ls[512];
    int t = threadIdx.x;
    int v = (t < nb) ? bsum[t] : 0;
    ls[t] = v;
    __syncthreads();
#pragma unroll
    for (int off = 1; off < 512; off <<= 1) {
        int a = (t >= off) ? ls[t - off] : 0;
        __syncthreads();
        ls[t] += a;
        __syncthreads();
    }
    if (t < nb) bsum[t] = ls[t] - v;
}

__global__ __launch_bounds__(256) void scan_add_k(int* __restrict__ ptr,
                                                  int* __restrict__ pos,
                                                  const int* __restrict__ bsum,
                                                  int n, int E) {
    int i = blockIdx.x * 256 + threadIdx.x;
    if (i == 0) ptr[n] = E;
    if (i < n) {
        int p = ptr[i] + bsum[blockIdx.x];
        ptr[i] = p;
        pos[i] = p;
    }
}

// XCD-partitioned fill (R10 win): partition = blockIdx & 7
__global__ __launch_bounds__(256) void csr_fill_part_k(
    const int* __restrict__ src, const int* __restrict__ dst,
    int* __restrict__ pos, int* __restrict__ csr, int E, int lo_step) {
    const int part = blockIdx.x & 7;
    const int e = (blockIdx.x >> 3) * 256 + threadIdx.x;
    if (e >= E) return;
    const int d = dst[e];
    const int lo = part * lo_step;
    const int hi = lo + lo_step;
    if (d < lo || d >= hi) return;
    const int p = atomicAdd(&pos[d], 1);
    csr[p] = src[e];
}

// ====== fp32 gather min (layer-1 x, D=32) ======
__global__ __launch_bounds__(256) void gather_min32_k(
    const float* __restrict__ feat, const int* __restrict__ ptr,
    const int* __restrict__ csr, float* __restrict__ agg, int n) {
    const int lane = threadIdx.x & 63;
    const int wave = (blockIdx.x * 256 + threadIdx.x) >> 6;
    const int node = wave * 2 + (lane >> 5);
    if (node >= n) return;
    const int fl = lane & 31;
    int e = ptr[node];
    const int end = ptr[node + 1];
    const bool empty = (e == end);
    float m = FLTMAX;
    for (; e + 7 < end; e += 8) {
        int s[8];
#pragma unroll
        for (int j = 0; j < 8; j++) s[j] = csr[e + j];
        float v[8];
#pragma unroll
        for (int j = 0; j < 8; j++) v[j] = feat[(size_t)s[j] * 32 + fl];
#pragma unroll
        for (int j = 0; j < 8; j++) m = fminf(m, v[j]);
    }
    for (; e < end; e++) m = fminf(m, feat[(size_t)csr[e] * 32 + fl]);
    agg[(size_t)node * 32 + fl] = empty ? 0.f : m;
}

// ====== fp32 gather min D=128 with fused BN+ReLU, 16 rows in flight ======
__global__ __launch_bounds__(256) void gather_min128_k(
    const float* __restrict__ feat, const int* __restrict__ ptr,
    const int* __restrict__ csr, const float* __restrict__ coef,
    float* __restrict__ agg, int n) {
    const int lane = threadIdx.x & 63;
    const int node = (blockIdx.x * 256 + threadIdx.x) >> 6;
    if (node >= n) return;
    const int fl = lane * 2;
    const float ca0 = coef[fl], ca1 = coef[fl + 1];
    const float cb0 = coef[128 + fl], cb1 = coef[128 + fl + 1];
    int e = ptr[node];
    const int end = ptr[node + 1];
    const bool empty = (e == end);
    float m0 = FLTMAX, m1 = FLTMAX;
    for (; e + 15 < end; e += 16) {
        int s[16];
#pragma unroll
        for (int j = 0; j < 16; j++) s[j] = csr[e + j];
        float2 v[16];
#pragma unroll
        for (int j = 0; j < 16; j++) v[j] = *(const float2*)(feat + (size_t)s[j] * 128 + fl);
#pragma unroll
        for (int j = 0; j < 16; j++) {
            m0 = fminf(m0, trf(v[j].x, ca0, cb0));
            m1 = fminf(m1, trf(v[j].y, ca1, cb1));
        }
    }
    for (; e + 3 < end; e += 4) {
        int s[4];
#pragma unroll
        for (int j = 0; j < 4; j++) s[j] = csr[e + j];
        float2 v[4];
#pragma unroll
        for (int j = 0; j < 4; j++) v[j] = *(const float2*)(feat + (size_t)s[j] * 128 + fl);
#pragma unroll
        for (int j = 0; j < 4; j++) {
            m0 = fminf(m0, trf(v[j].x, ca0, cb0));
            m1 = fminf(m1, trf(v[j].y, ca1, cb1));
        }
    }
    for (; e < end; e++) {
        const float2 v = *(const float2*)(feat + (size_t)csr[e] * 128 + fl);
        m0 = fminf(m0, trf(v.x, ca0, cb0));
        m1 = fminf(m1, trf(v.y, ca1, cb1));
    }
    float2 o;
    o.x = empty ? 0.f : m0;
    o.y = empty ? 0.f : m1;
    *(float2*)(agg + (size_t)node * 128 + fl) = o;
}

// ====== bf16 gather min over A_cat right half -> left half, 16 rows in flight ======
__global__ __launch_bounds__(256) void gather_bf_k(
    u16* __restrict__ Acat, const int* __restrict__ ptr,
    const int* __restrict__ csr, int n) {
    const int lane = threadIdx.x & 63;
    const int node = (blockIdx.x * 256 + threadIdx.x) >> 6;
    if (node >= n) return;
    const int fl = lane * 2;
    int e = ptr[node];
    const int end = ptr[node + 1];
    u32 outv = 0;
    if (e != end) {
        float m0 = FLTMAX, m1 = FLTMAX;
        for (; e + 15 < end; e += 16) {
            int s[16];
#pragma unroll
            for (int j = 0; j < 16; j++) s[j] = csr[e + j];
            u32 v[16];
#pragma unroll
            for (int j = 0; j < 16; j++) v[j] = *(const u32*)(Acat + (size_t)s[j] * 256 + 128 + fl);
#pragma unroll
            for (int j = 0; j < 16; j++) {
                m0 = fminf(m0, __uint_as_float(v[j] << 16));
                m1 = fminf(m1, __uint_as_float(v[j] & 0xffff0000u));
            }
        }
        for (; e + 3 < end; e += 4) {
            int s[4];
#pragma unroll
            for (int j = 0; j < 4; j++) s[j] = csr[e + j];
            u32 v[4];
#pragma unroll
            for (int j = 0; j < 4; j++) v[j] = *(const u32*)(Acat + (size_t)s[j] * 256 + 128 + fl);
#pragma unroll
            for (int j = 0; j < 4; j++) {
                m0 = fminf(m0, __uint_as_float(v[j] << 16));
                m1 = fminf(m1, __uint_as_float(v[j] & 0xffff0000u));
            }
        }
        for (; e < end; e++) {
            u32 v = *(const u32*)(Acat + (size_t)csr[e] * 256 + 128 + fl);
            m0 = fminf(m0, __uint_as_float(v << 16));
            m1 = fminf(m1, __uint_as_float(v & 0xffff0000u));
        }
        outv = (__float_as_uint(m0) >> 16) | (__float_as_uint(m1) & 0xffff0000u);
    }
    *(u32*)(Acat + (size_t)node * 256 + fl) = outv;
}

__global__ __launch_bounds__(256) void gather_min3_k(
    const float* __restrict__ feat, const int* __restrict__ ptr,
    const int* __restrict__ csr, float* __restrict__ agg, int n) {
    int i = blockIdx.x * 256 + threadIdx.x;
    if (i >= n) return;
    int e = ptr[i], end = ptr[i + 1];
    bool empty = (e == end);
    float m0 = FLTMAX, m1 = FLTMAX, m2 = FLTMAX;
    for (; e < end; e++) {
        const float* r = feat + (size_t)csr[e] * 3;
        m0 = fminf(m0, r[0]);
        m1 = fminf(m1, r[1]);
        m2 = fminf(m2, r[2]);
    }
    agg[(size_t)i * 3 + 0] = empty ? 0.f : m0;
    agg[(size_t)i * 3 + 1] = empty ? 0.f : m1;
    agg[(size_t)i * 3 + 2] = empty ? 0.f : m2;
}

// ====== convert bn_relu(h) (D=128) -> bf16 into A_cat right half ======
__global__ __launch_bounds__(256) void convert_k(
    const float* __restrict__ h, const float* __restrict__ coef,
    u16* __restrict__ Acat, int n) {
    int t = blockIdx.x * 256 + threadIdx.x;
    int total = n * 32;
    if (t >= total) return;
    int i = t >> 5;
    int dq = (t & 31) * 4;
    const float4 hv = *(const float4*)(h + (size_t)i * 128 + dq);
    const float4 ca = *(const float4*)(coef + dq);
    const float4 cb = *(const float4*)(coef + 128 + dq);
    ushort4 o;
    o.x = f2bf(trf(hv.x, ca.x, cb.x));
    o.y = f2bf(trf(hv.y, ca.y, cb.y));
    o.z = f2bf(trf(hv.z, ca.z, cb.z));
    o.w = f2bf(trf(hv.w, ca.w, cb.w));
    *(ushort4*)(Acat + (size_t)i * 256 + 128 + dq) = o;
}

// ====== weight prep: WT[c][k] = bf16( k<128 ? wl[k][c] : wr[k-128][c] ) ======
__global__ __launch_bounds__(256) void wprep_k(
    const float* __restrict__ wl, const float* __restrict__ wr,
    u16* __restrict__ WT, int N) {
    int t = blockIdx.x * 256 + threadIdx.x;
    if (t >= N * 256) return;
    int c = t >> 8;
    int k = t & 255;
    float v = (k < 128) ? wl[k * N + c] : wr[(k - 128) * N + c];
    WT[(size_t)c * 256 + k] = f2bf(v);
}

// ====== bf16 MFMA GEMM: out[n][128] = A_cat[n][256] @ W_cat[256][128] + bias ======
__global__ __launch_bounds__(256) void gemm_bf_k(
    const u16* __restrict__ A, const u16* __restrict__ WT,
    const float* __restrict__ bl1, const float* __restrict__ bl2,
    float* __restrict__ out, int n) {
    constexpr int NT = 8;
    const int tid = threadIdx.x;
    const int wave = tid >> 6, lane = tid & 63;
    const int quad = lane >> 4, l16 = lane & 15;
    const int row0 = blockIdx.x * 64 + wave * 16;
    const int rowA = min(row0 + l16, n - 1);
    const uint4* Arow = (const uint4*)(A + (size_t)rowA * 256) + quad;

    bf16x8 a[8];
#pragma unroll
    for (int kc = 0; kc < 8; kc++) {
        U16x8 u; u.u = Arow[kc * 4];
        a[kc] = u.b;
    }
    f32x4 acc[NT];
#pragma unroll
    for (int i = 0; i < NT; i++) acc[i] = (f32x4){0.f, 0.f, 0.f, 0.f};
#pragma unroll
    for (int nt = 0; nt < NT; nt++) {
        const uint4* Brow = (const uint4*)(WT + (size_t)(nt * 16 + l16) * 256) + quad;
#pragma unroll
        for (int kc = 0; kc < 8; kc++) {
            U16x8 u; u.u = Brow[kc * 4];
            acc[nt] = __builtin_amdgcn_mfma_f32_16x16x32_bf16(a[kc], u.b, acc[nt], 0, 0, 0);
        }
    }
#pragma unroll
    for (int nt = 0; nt < NT; nt++) {
        const int col = nt * 16 + l16;
        const float bias = (col < 64) ? bl1[col] : bl2[col - 64];
#pragma unroll
        for (int r = 0; r < 4; r++) {
            const int row = row0 + quad * 4 + r;
            if (row < n) out[(size_t)row * 128 + col] = acc[nt][r] + bias;
        }
    }
}

// ====== fp32 linear (layer-1, K=32 -> 128) ======
__global__ __launch_bounds__(256) void linear1_k(
    const float* __restrict__ agg, const float* __restrict__ h,
    const float* __restrict__ wl, const float* __restrict__ bl,
    const float* __restrict__ wr, float* __restrict__ out, int n) {
    constexpr int DOUT = 128, CT = 32, RB = 32;
    const int ct = threadIdx.x % CT;
    const int rt = threadIdx.x / CT;
    const int col = ct * 4;
    const int row0 = blockIdx.x * RB + rt * 4;
    int r_idx[4];
#pragma unroll
    for (int r = 0; r < 4; r++) r_idx[r] = min(row0 + r, n - 1);
    float4 acc[4] = {};
#pragma unroll 2
    for (int k0 = 0; k0 < 32; k0 += 4) {
        float4 wlv[4], wrv[4];
#pragma unroll
        for (int j = 0; j < 4; j++) {
            wlv[j] = *(const float4*)(wl + (size_t)(k0 + j) * DOUT + col);
            wrv[j] = *(const float4*)(wr + (size_t)(k0 + j) * DOUT + col);
        }
#pragma unroll
        for (int r = 0; r < 4; r++) {
            const float4 av = *(const float4*)(agg + (size_t)r_idx[r] * 32 + k0);
            const float4 hv = *(const float4*)(h + (size_t)r_idx[r] * 32 + k0);
#pragma unroll
            for (int j = 0; j < 4; j++) {
                const float aa = j == 0 ? av.x : j == 1 ? av.y : j == 2 ? av.z : av.w;
                const float bb = j == 0 ? hv.x : j == 1 ? hv.y : j == 2 ? hv.z : hv.w;
                acc[r].x += aa * wlv[j].x + bb * wrv[j].x;
                acc[r].y += aa * wlv[j].y + bb * wrv[j].y;
                acc[r].z += aa * wlv[j].z + bb * wrv[j].z;
                acc[r].w += aa * wlv[j].w + bb * wrv[j].w;
            }
        }
    }
    const float4 bv = *(const float4*)(bl + col);
#pragma unroll
    for (int r = 0; r < 4; r++) {
        if (row0 + r < n) {
            float4 o = acc[r];
            o.x += bv.x; o.y += bv.y; o.z += bv.z; o.w += bv.w;
            *(float4*)(out + (size_t)(row0 + r) * DOUT + col) = o;
        }
    }
}

// ====== fp32 linear (layer-2, K=128 -> 64), LDS-staged A/h tiles ======
__global__ __launch_bounds__(256) void linear2_k(
    const float* __restrict__ agg, const float* __restrict__ h,
    const float* __restrict__ coef, const float* __restrict__ wl,
    const float* __restrict__ bl, const float* __restrict__ wr,
    float* __restrict__ out, int n) {
    constexpr int DIN = 128, DOUT = 64, CT = 16, RB = 64, LDW = 132;
    __shared__ float Ash[RB * LDW];
    __shared__ float Hsh[RB * LDW];
    const int tid = threadIdx.x;
    const int base = blockIdx.x * RB;
    {
        const int sr = tid >> 2;
        const int sc = tid & 3;
        const int grow = min(base + sr, n - 1);
        const float* ar = agg + (size_t)grow * DIN;
        const float* hr = h + (size_t)grow * DIN;
#pragma unroll
        for (int c = 0; c < 8; c++) {
            const int col = (sc + c * 4) * 4;
            const float4 av = *(const float4*)(ar + col);
            float4 hv = *(const float4*)(hr + col);
            const float4 ca = *(const float4*)(coef + col);
            const float4 cb = *(const float4*)(coef + DIN + col);
            hv.x = trf(hv.x, ca.x, cb.x); hv.y = trf(hv.y, ca.y, cb.y);
            hv.z = trf(hv.z, ca.z, cb.z); hv.w = trf(hv.w, ca.w, cb.w);
            *(float4*)(Ash + sr * LDW + col) = av;
            *(float4*)(Hsh + sr * LDW + col) = hv;
        }
    }
    __syncthreads();
    const int ct = tid % CT;
    const int rt = tid / CT;
    const int col = ct * 4;
    const int row0 = base + rt * 4;
    float4 acc[4] = {};
#pragma unroll 2
    for (int k0 = 0; k0 < DIN; k0 += 4) {
        float4 wlv[4], wrv[4];
#pragma unroll
        for (int j = 0; j < 4; j++) {
            wlv[j] = *(const float4*)(wl + (size_t)(k0 + j) * DOUT + col);
            wrv[j] = *(const float4*)(wr + (size_t)(k0 + j) * DOUT + col);
        }
#pragma unroll
        for (int r = 0; r < 4; r++) {
            const float4 av = *(const float4*)(Ash + (rt * 4 + r) * LDW + k0);
            const float4 hv = *(const float4*)(Hsh + (rt * 4 + r) * LDW + k0);
#pragma unroll
            for (int j = 0; j < 4; j++) {
                const float aa = j == 0 ? av.x : j == 1 ? av.y : j == 2 ? av.z : av.w;
                const float bb = j == 0 ? hv.x : j == 1 ? hv.y : j == 2 ? hv.z : hv.w;
                acc[r].x += aa * wlv[j].x + bb * wrv[j].x;
                acc[r].y += aa * wlv[j].y + bb * wrv[j].y;
                acc[r].z += aa * wlv[j].z + bb * wrv[j].z;
                acc[r].w += aa * wlv[j].w + bb * wrv[j].w;
            }
        }
    }
    const float4 bv = *(const float4*)(bl + col);
#pragma unroll
    for (int r = 0; r < 4; r++) {
        if (row0 + r < n) {
            float4 o = acc[r];
            o.x += bv.x; o.y += bv.y; o.z += bv.z; o.w += bv.w;
            *(float4*)(out + (size_t)(row0 + r) * DOUT + col) = o;
        }
    }
}

// ====== sh1 linear: concat([x(32), rm(3)]) -> 128, raw operands ======
__global__ __launch_bounds__(256) void linear_sh4_k(
    const float* __restrict__ aggx, const float* __restrict__ x,
    const float* __restrict__ aggr, const float* __restrict__ rm,
    const float* __restrict__ wl, const float* __restrict__ bl,
    const float* __restrict__ wr, float* __restrict__ out, int n) {
    constexpr int DOUT = 128, CT = 32, RB = 32;
    const int ct = threadIdx.x % CT;
    const int rt = threadIdx.x / CT;
    const int col = ct * 4;
    const int row0 = blockIdx.x * RB + rt * 4;
    int r_idx[4];
#pragma unroll
    for (int r = 0; r < 4; r++) r_idx[r] = min(row0 + r, n - 1);
    float4 acc[4] = {};
#pragma unroll 2
    for (int k0 = 0; k0 < 32; k0 += 4) {
        float4 wlv[4], wrv[4];
#pragma unroll
        for (int j = 0; j < 4; j++) {
            wlv[j] = *(const float4*)(wl + (size_t)(k0 + j) * DOUT + col);
            wrv[j] = *(const float4*)(wr + (size_t)(k0 + j) * DOUT + col);
        }
#pragma unroll
        for (int r = 0; r < 4; r++) {
            const float4 av = *(const float4*)(aggx + (size_t)r_idx[r] * 32 + k0);
            const float4 hv = *(const float4*)(x + (size_t)r_idx[r] * 32 + k0);
#pragma unroll
            for (int j = 0; j < 4; j++) {
                const float aa = j == 0 ? av.x : j == 1 ? av.y : j == 2 ? av.z : av.w;
                const float bb = j == 0 ? hv.x : j == 1 ? hv.y : j == 2 ? hv.z : hv.w;
                acc[r].x += aa * wlv[j].x + bb * wrv[j].x;
                acc[r].y += aa * wlv[j].y + bb * wrv[j].y;
                acc[r].z += aa * wlv[j].z + bb * wrv[j].z;
                acc[r].w += aa * wlv[j].w + bb * wrv[j].w;
            }
        }
    }
#pragma unroll
    for (int k = 0; k < 3; k++) {
        const float4 wlv = *(const float4*)(wl + (size_t)(32 + k) * DOUT + col);
        const float4 wrv = *(const float4*)(wr + (size_t)(32 + k) * DOUT + col);
#pragma unroll
        for (int r = 0; r < 4; r++) {
            const float a = aggr[(size_t)r_idx[r] * 3 + k];
            const float b = rm[(size_t)r_idx[r] * 3 + k];
            acc[r].x += a * wlv.x + b * wrv.x;
            acc[r].y += a * wlv.y + b * wrv.y;
            acc[r].z += a * wlv.z + b * wrv.z;
            acc[r].w += a * wlv.w + b * wrv.w;
        }
    }
    const float4 bv = *(const float4*)(bl + col);
#pragma unroll
    for (int r = 0; r < 4; r++) {
        if (row0 + r < n) {
            float4 o = acc[r];
            o.x += bv.x; o.y += bv.y; o.z += bv.z; o.w += bv.w;
            *(float4*)(out + (size_t)(row0 + r) * DOUT + col) = o;
        }
    }
}

// ---- per-column sum / sumsq with LDS pre-reduction ----
template <int D>
__global__ __launch_bounds__(256) void colstats_k(
    const float* __restrict__ x, float* __restrict__ stats, int total) {
    __shared__ float ls[256];
    int t0 = blockIdx.x * 256 + threadIdx.x;
    int stride = gridDim.x * 256;
    float s = 0.f, s2 = 0.f;
    for (int t = t0; t < total; t += stride) {
        float v = x[t];
        s += v;
        s2 += v * v;
    }
    int col = threadIdx.x % D;
    ls[threadIdx.x] = s;
    __syncthreads();
    if (threadIdx.x < D) {
        float a = s;
        for (int u = threadIdx.x + D; u < 256; u += D) a += ls[u];
        atomicAdd(&stats[col], a);
    }
    __syncthreads();
    ls[threadIdx.x] = s2;
    __syncthreads();
    if (threadIdx.x < D) {
        float a = s2;
        for (int u = threadIdx.x + D; u < 256; u += D) a += ls[u];
        atomicAdd(&stats[D + col], a);
    }
}

// ====== per-layer BN coefficients ======
template <int D>
__global__ void coef_k(const float* __restrict__ stats, const float* __restrict__ g,
                       const float* __restrict__ bb, float* __restrict__ coef,
                       float invN) {
    int d = threadIdx.x;
    if (d >= D) return;
    float mu = stats[d] * invN;
    float var = stats[D + d] * invN - mu * mu;
    float a = rsqrtf(var + 1e-5f) * g[d];
    coef[d] = a;
    coef[D + d] = bb[d] - mu * a;
}

__global__ void coef_dual_k(const float* __restrict__ stats,
                            const float* __restrict__ gR, const float* __restrict__ bR,
                            const float* __restrict__ gM, const float* __restrict__ bM,
                            float* __restrict__ coefR, float* __restrict__ coefM,
                            float invN) {
    int d = threadIdx.x;
    if (d >= 128) return;
    float mu = stats[d] * invN;
    float var = stats[128 + d] * invN - mu * mu;
    bool isR = d < 64;
    int c = isR ? d : d - 64;
    float g = isR ? gR[c] : gM[c];
    float be = isR ? bR[c] : bM[c];
    float a = rsqrtf(var + 1e-5f) * g;
    float* co = isR ? coefR : coefM;
    co[c] = a;
    co[64 + c] = be - mu * a;
}

// ====== rm head fused: gather(h2,D=64) + 64->3 linear + log_softmax + labels ======
__global__ __launch_bounds__(256) void rm_fused_k(
    const float* __restrict__ h2, const float* __restrict__ coef,
    const int* __restrict__ ptr, const int* __restrict__ csr,
    const float* __restrict__ wl, const float* __restrict__ bl,
    const float* __restrict__ wr, float* __restrict__ rmb,
    float* __restrict__ ls_out, float* __restrict__ lab, int n) {
    const int lane = threadIdx.x & 63;
    const int node = (blockIdx.x * 256 + threadIdx.x) >> 6;
    if (node >= n) return;
    const float a = coef[lane], b = coef[64 + lane];
    int e = ptr[node];
    const int end = ptr[node + 1];
    const bool empty = (e == end);
    float m = FLTMAX;
    for (; e + 15 < end; e += 16) {
        int s[16];
#pragma unroll
        for (int j = 0; j < 16; j++) s[j] = csr[e + j];
        float v[16];
#pragma unroll
        for (int j = 0; j < 16; j++) v[j] = h2[(size_t)s[j] * 64 + lane];
#pragma unroll
        for (int j = 0; j < 16; j++) m = fminf(m, trf(v[j], a, b));
    }
    for (; e + 3 < end; e += 4) {
        int s[4];
#pragma unroll
        for (int j = 0; j < 4; j++) s[j] = csr[e + j];
        float v[4];
#pragma unroll
        for (int j = 0; j < 4; j++) v[j] = h2[(size_t)s[j] * 64 + lane];
#pragma unroll
        for (int j = 0; j < 4; j++) m = fminf(m, trf(v[j], a, b));
    }
    for (; e < end; e++) m = fminf(m, trf(h2[(size_t)csr[e] * 64 + lane], a, b));
    m = empty ? 0.f : m;
    const float hv = trf(h2[(size_t)node * 64 + lane], a, b);
    float c0 = m * wl[lane * 3 + 0] + hv * wr[lane * 3 + 0];
    float c1 = m * wl[lane * 3 + 1] + hv * wr[lane * 3 + 1];
    float c2 = m * wl[lane * 3 + 2] + hv * wr[lane * 3 + 2];
#pragma unroll
    for (int off = 1; off < 64; off <<= 1) {
        c0 += __shfl_xor(c0, off);
        c1 += __shfl_xor(c1, off);
        c2 += __shfl_xor(c2, off);
    }
    const float r0 = c0 + bl[0], r1 = c1 + bl[1], r2 = c2 + bl[2];
    if (lane < 3) {
        const float r = lane == 0 ? r0 : lane == 1 ? r1 : r2;
        rmb[(size_t)node * 3 + lane] = r;
        const float mx = fmaxf(r0, fmaxf(r1, r2));
        const float lse = mx + logf(expf(r0 - mx) + expf(r1 - mx) + expf(r2 - mx));
        ls_out[(size_t)node * 3 + lane] = r - lse;
        if (lane == 0) lab[node] = (r2 > r0 && r2 > r1) ? 1.f : 0.f;
    }
}

// ====== final heads: rtmd[n][128] (rt|md) with fused BN+ReLU ======
__global__ __launch_bounds__(256) void final_k(
    const float* __restrict__ rtmd,
    const float* __restrict__ cR, const float* __restrict__ cM,
    const float* __restrict__ rtw, const float* __restrict__ rtb,
    const float* __restrict__ mdw, const float* __restrict__ mdb,
    const float* __restrict__ lab, float* __restrict__ out_rt,
    float* __restrict__ out_md, int n) {
    int i = blockIdx.x * 256 + threadIdx.x;
    if (i >= n) return;
    const float* rr = rtmd + (size_t)i * 128;
    const float* mr = rr + 64;
    float a = rtb[0], b = mdb[0];
#pragma unroll 8
    for (int k = 0; k < 64; k++) {
        a += trf(rr[k], cR[k], cR[64 + k]) * rtw[k];
        b += trf(mr[k], cM[k], cM[64 + k]) * mdw[k];
    }
    float l = lab[i];
    out_rt[i] = a * l;
    out_md[i] = b * l;
}

extern "C" void kernel_launch(void* const* d_in, const int* in_sizes, int n_in,
                              void* d_out, int out_size, void* d_ws, size_t ws_size,
                              hipStream_t stream) {
    const float* x = (const float*)d_in[0];
    const int* ei = (const int*)d_in[1];
    const int E = in_sizes[1] / 2;
    const int n = in_sizes[0] / 32;
    const int* src = ei;
    const int* dst = ei + E;

    const float* rm1_wl = (const float*)d_in[2];
    const float* rm1_bl = (const float*)d_in[3];
    const float* rm1_wr = (const float*)d_in[4];
    const float* rmn1_g = (const float*)d_in[5];
    const float* rmn1_b = (const float*)d_in[6];
    const float* rm2_wl = (const float*)d_in[7];
    const float* rm2_bl = (const float*)d_in[8];
    const float* rm2_wr = (const float*)d_in[9];
    const float* rmn2_g = (const float*)d_in[10];
    const float* rmn2_b = (const float*)d_in[11];
    const float* rm4_wl = (const float*)d_in[12];
    const float* rm4_bl = (const float*)d_in[13];
    const float* rm4_wr = (const float*)d_in[14];
    const float* sh1_wl = (const float*)d_in[15];
    const float* sh1_bl = (const float*)d_in[16];
    const float* sh1_wr = (const float*)d_in[17];
    const float* shn1_g = (const float*)d_in[18];
    const float* shn1_b = (const float*)d_in[19];
    const float* rt1_wl = (const float*)d_in[20];
    const float* rt1_bl = (const float*)d_in[21];
    const float* rt1_wr = (const float*)d_in[22];
    const float* rtn1_g = (const float*)d_in[23];
    const float* rtn1_b = (const float*)d_in[24];
    const float* rt3_w = (const float*)d_in[25];
    const float* rt3_b = (const float*)d_in[26];
    const float* md1_wl = (const float*)d_in[27];
    const float* md1_bl = (const float*)d_in[28];
    const float* md1_wr = (const float*)d_in[29];
    const float* mdn1_g = (const float*)d_in[30];
    const float* mdn1_b = (const float*)d_in[31];
    const float* md3_w = (const float*)d_in[32];
    const float* md3_b = (const float*)d_in[33];

    // workspace layout; shbuf serves as fp32 aggB (layer 2), then bf16 Acat (dual)
    char* w = (char*)d_ws;
    float* aggX  = (float*)w; w += (size_t)n * 32 * 4;
    float* h1    = (float*)w; w += (size_t)n * 128 * 4;   // h1 raw, later h3 raw
    char*  shbuf = w;         w += (size_t)n * 512;       // aggB fp32 [n][128] | Acat bf16 [n][256]
    float* h2rt  = (float*)w; w += (size_t)n * 128 * 4;   // h2 [n][64], later rtmd [n][128]
    float* rmb   = (float*)w; w += (size_t)n * 3 * 4;
    float* aggR  = (float*)w; w += (size_t)n * 3 * 4;
    float* lab   = (float*)w; w += (size_t)n * 4;
    float* stats = (float*)w; w += 1024 * 4;
    float* coef  = (float*)w; w += 1024 * 4;
    u16*   WTD   = (u16*)w;   w += (size_t)128 * 256 * 2;
    int* ptr  = (int*)w; w += (size_t)(n + 1) * 4;
    int* pos  = (int*)w; w += (size_t)n * 4;
    int* bsum = (int*)w; w += 1024 * 4;
    int* csr  = (int*)w; w += (size_t)E * 4;

    float* aggB = (float*)shbuf;
    u16*   Acat = (u16*)shbuf;
    float* h2 = h2rt;
    float* rtmd = h2rt;
    float* stats1 = stats, *stats2 = stats + 256, *statsSh = stats + 512, *statsD = stats + 768;
    float* coef1 = coef, *coef2 = coef + 256, *coefSh = coef + 384;
    float* coefRt = coef + 640, *coefMd = coef + 768;

    float* out = (float*)d_out;
    float* out_ls = out;
    float* out_rt = out + (size_t)3 * n;
    float* out_md = out + (size_t)4 * n;

    const float invN = 1.f / (float)n;
    auto cdiv = [](int a, int b) { return (a + b - 1) / b; };
    const int nb = cdiv(n, 256);

    hipMemsetAsync(stats, 0, 1024 * 4, stream);
    hipMemsetAsync(pos, 0, (size_t)n * 4, stream);

    // ---- CSR build + dual-weight prep (feature-independent)
    hist_k<<<cdiv(E, 256), 256, 0, stream>>>(dst, pos, E);
    wprep_k<<<64, 256, 0, stream>>>(rt1_wl, rt1_wr, WTD, 64);
    wprep_k<<<64, 256, 0, stream>>>(md1_wl, md1_wr, WTD + (size_t)64 * 256, 64);
    scan_block_k<<<nb, 256, 0, stream>>>(pos, ptr, bsum, n);
    scan_bsum_k<<<1, 512, 0, stream>>>(bsum, nb);
    scan_add_k<<<nb, 256, 0, stream>>>(ptr, pos, bsum, n, E);
    csr_fill_part_k<<<cdiv(E, 256) * 8, 256, 0, stream>>>(src, dst, pos, csr, E, cdiv(n, 8));

    // ---- layer 1 (fp32): agg(x) -> linear -> h1; stats -> coef1
    gather_min32_k<<<cdiv(n, 8), 256, 0, stream>>>(x, ptr, csr, aggX, n);
    linear1_k<<<cdiv(n, 32), 256, 0, stream>>>(aggX, x, rm1_wl, rm1_bl, rm1_wr, h1, n);
    colstats_k<128><<<256, 256, 0, stream>>>(h1, stats1, n * 128);
    coef_k<128><<<1, 128, 0, stream>>>(stats1, rmn1_g, rmn1_b, coef1, invN);

    // ---- layer 2 (fp32, label-critical): gather(bnrelu(h1)) -> linear -> h2
    gather_min128_k<<<cdiv(n, 4), 256, 0, stream>>>(h1, ptr, csr, coef1, aggB, n);
    linear2_k<<<cdiv(n, 64), 256, 0, stream>>>(aggB, h1, coef1, rm2_wl, rm2_bl, rm2_wr, h2, n);
    colstats_k<64><<<256, 256, 0, stream>>>(h2, stats2, n * 64);
    coef_k<64><<<1, 64, 0, stream>>>(stats2, rmn2_g, rmn2_b, coef2, invN);

    // ---- rm head (fp32): fused gather + linear + log_softmax + labels
    rm_fused_k<<<cdiv(n, 4), 256, 0, stream>>>(h2, coef2, ptr, csr, rm4_wl, rm4_bl, rm4_wr, rmb, out_ls, lab, n);

    // ---- sh1 (fp32): agg(rm); linear concat([x,rm]) -> h3 (h1 buf); stats -> coefSh
    gather_min3_k<<<cdiv(n, 256), 256, 0, stream>>>(rmb, ptr, csr, aggR, n);
    linear_sh4_k<<<cdiv(n, 32), 256, 0, stream>>>(aggX, x, aggR, rmb, sh1_wl, sh1_bl, sh1_wr, h1, n);
    colstats_k<128><<<256, 256, 0, stream>>>(h1, statsSh, n * 128);
    coef_k<128><<<1, 128, 0, stream>>>(statsSh, shn1_g, shn1_b, coefSh, invN);

    // ---- dual rt/md (bf16 MFMA, continuous path):
    convert_k<<<cdiv(n * 32, 256), 256, 0, stream>>>(h1, coefSh, Acat, n);
    gather_bf_k<<<cdiv(n, 4), 256, 0, stream>>>(Acat, ptr, csr, n);
    gemm_bf_k<<<cdiv(n, 64), 256, 0, stream>>>(Acat, WTD, rt1_bl, md1_bl, rtmd, n);
    colstats_k<128><<<256, 256, 0, stream>>>(rtmd, statsD, n * 128);
    coef_dual_k<<<1, 128, 0, stream>>>(statsD, rtn1_g, rtn1_b, mdn1_g, mdn1_b, coefRt, coefMd, invN);

    // ---- final heads
    final_k<<<cdiv(n, 256), 256, 0, stream>>>(rtmd, coefRt, coefMd,
                                              rt3_w, rt3_b, md3_w, md3_b, lab,
                                              out_rt, out_md, n);
}

// Round 12
// 988.567 us; speedup vs baseline: 1.3456x; 1.0449x over previous
//
#include <hip/hip_runtime.h>

#define FLTMAX 3.402823466e+38f
#define DEV __device__ __forceinline__

typedef unsigned short u16;
typedef unsigned int u32;
typedef __bf16 bf16_t;
typedef bf16_t bf16x8 __attribute__((ext_vector_type(8)));
typedef float f32x4 __attribute__((ext_vector_type(4)));

union U16x8 { uint4 u; bf16x8 b; };

DEV float trf(float v, float a, float b) { return fmaxf(fmaf(v, a, b), 0.f); }

// round-to-nearest-even fp32 -> bf16 bits (finite inputs)
DEV u16 f2bf(float f) {
    u32 u = __float_as_uint(f);
    return (u16)((u + 0x7FFFu + ((u >> 16) & 1u)) >> 16);
}

// ================= CSR build =================
__global__ __launch_bounds__(256) void hist_k(const int* __restrict__ dst,
                                              int* __restrict__ deg, int E) {
    int e = blockIdx.x * 256 + threadIdx.x;
    if (e >= E) return;
    atomicAdd(&deg[dst[e]], 1);
}

__global__ __launch_bounds__(256) void scan_block_k(const int* __restrict__ deg,
                                                    int* __restrict__ ptr,
                                                    int* __restrict__ bsum, int n) {
    __shared__ int ls[256];
    int i = blockIdx.x * 256 + threadIdx.x;
    int v = (i < n) ? deg[i] : 0;
    ls[threadIdx.x] = v;
    __syncthreads();
#pragma unroll
    for (int off = 1; off < 256; off <<= 1) {
        int a = (threadIdx.x >= off) ? ls[threadIdx.x - off] : 0;
        __syncthreads();
        ls[threadIdx.x] += a;
        __syncthreads();
    }
    if (i < n) ptr[i] = ls[threadIdx.x] - v;
    if (threadIdx.x == 255) bsum[blockIdx.x] = ls[255];
}

__global__ __launch_bounds__(512) void scan_bsum_k(int* __restrict__ bsum, int nb) {
    __shared__ int ls[512];
    int t = threadIdx.x;
    int v = (t < nb) ? bsum[t] : 0;
    ls[t] = v;
    __syncthreads();
#pragma unroll
    for (int off = 1; off < 512; off <<= 1) {
        int a = (t >= off) ? ls[t - off] : 0;
        __syncthreads();
        ls[t] += a;
        __syncthreads();
    }
    if (t < nb) bsum[t] = ls[t] - v;
}

__global__ __launch_bounds__(256) void scan_add_k(int* __restrict__ ptr,
                                                  int* __restrict__ pos,
                                                  const int* __restrict__ bsum,
                                                  int n, int E) {
    int i = blockIdx.x * 256 + threadIdx.x;
    if (i == 0) ptr[n] = E;
    if (i < n) {
        int p = ptr[i] + bsum[blockIdx.x];
        ptr[i] = p;
        pos[i] = p;
    }
}

// XCD-partitioned fill (R10 win): partition = blockIdx & 7
__global__ __launch_bounds__(256) void csr_fill_part_k(
    const int* __restrict__ src, const int* __restrict__ dst,
    int* __restrict__ pos, int* __restrict__ csr, int E, int lo_step) {
    const int part = blockIdx.x & 7;
    const int e = (blockIdx.x >> 3) * 256 + threadIdx.x;
    if (e >= E) return;
    const int d = dst[e];
    const int lo = part * lo_step;
    const int hi = lo + lo_step;
    if (d < lo || d >= hi) return;
    const int p = atomicAdd(&pos[d], 1);
    csr[p] = src[e];
}

// ====== fp32 gather min (layer-1 x, D=32) ======
__global__ __launch_bounds__(256) void gather_min32_k(
    const float* __restrict__ feat, const int* __restrict__ ptr,
    const int* __restrict__ csr, float* __restrict__ agg, int n) {
    const int lane = threadIdx.x & 63;
    const int wave = (blockIdx.x * 256 + threadIdx.x) >> 6;
    const int node = wave * 2 + (lane >> 5);
    if (node >= n) return;
    const int fl = lane & 31;
    int e = ptr[node];
    const int end = ptr[node + 1];
    const bool empty = (e == end);
    float m = FLTMAX;
    for (; e + 7 < end; e += 8) {
        int s[8];
#pragma unroll
        for (int j = 0; j < 8; j++) s[j] = csr[e + j];
        float v[8];
#pragma unroll
        for (int j = 0; j < 8; j++) v[j] = feat[(size_t)s[j] * 32 + fl];
#pragma unroll
        for (int j = 0; j < 8; j++) m = fminf(m, v[j]);
    }
    for (; e < end; e++) m = fminf(m, feat[(size_t)csr[e] * 32 + fl]);
    agg[(size_t)node * 32 + fl] = empty ? 0.f : m;
}

// ====== fp32 gather min D=128 with fused BN+ReLU, 8 rows in flight (R10 form) ======
__global__ __launch_bounds__(256) void gather_min128_k(
    const float* __restrict__ feat, const int* __restrict__ ptr,
    const int* __restrict__ csr, const float* __restrict__ coef,
    float* __restrict__ agg, int n) {
    const int lane = threadIdx.x & 63;
    const int node = (blockIdx.x * 256 + threadIdx.x) >> 6;
    if (node >= n) return;
    const int fl = lane * 2;
    const float ca0 = coef[fl], ca1 = coef[fl + 1];
    const float cb0 = coef[128 + fl], cb1 = coef[128 + fl + 1];
    int e = ptr[node];
    const int end = ptr[node + 1];
    const bool empty = (e == end);
    float m0 = FLTMAX, m1 = FLTMAX;
    for (; e + 7 < end; e += 8) {
        int s[8];
#pragma unroll
        for (int j = 0; j < 8; j++) s[j] = csr[e + j];
        float2 v[8];
#pragma unroll
        for (int j = 0; j < 8; j++) v[j] = *(const float2*)(feat + (size_t)s[j] * 128 + fl);
#pragma unroll
        for (int j = 0; j < 8; j++) {
            m0 = fminf(m0, trf(v[j].x, ca0, cb0));
            m1 = fminf(m1, trf(v[j].y, ca1, cb1));
        }
    }
    for (; e + 3 < end; e += 4) {
        int s[4];
#pragma unroll
        for (int j = 0; j < 4; j++) s[j] = csr[e + j];
        float2 v[4];
#pragma unroll
        for (int j = 0; j < 4; j++) v[j] = *(const float2*)(feat + (size_t)s[j] * 128 + fl);
#pragma unroll
        for (int j = 0; j < 4; j++) {
            m0 = fminf(m0, trf(v[j].x, ca0, cb0));
            m1 = fminf(m1, trf(v[j].y, ca1, cb1));
        }
    }
    for (; e < end; e++) {
        const float2 v = *(const float2*)(feat + (size_t)csr[e] * 128 + fl);
        m0 = fminf(m0, trf(v.x, ca0, cb0));
        m1 = fminf(m1, trf(v.y, ca1, cb1));
    }
    float2 o;
    o.x = empty ? 0.f : m0;
    o.y = empty ? 0.f : m1;
    *(float2*)(agg + (size_t)node * 128 + fl) = o;
}

// ====== bf16 gather min over A_cat right half -> left half, 16 rows in flight ======
__global__ __launch_bounds__(256) void gather_bf_k(
    u16* __restrict__ Acat, const int* __restrict__ ptr,
    const int* __restrict__ csr, int n) {
    const int lane = threadIdx.x & 63;
    const int node = (blockIdx.x * 256 + threadIdx.x) >> 6;
    if (node >= n) return;
    const int fl = lane * 2;
    int e = ptr[node];
    const int end = ptr[node + 1];
    u32 outv = 0;
    if (e != end) {
        float m0 = FLTMAX, m1 = FLTMAX;
        for (; e + 15 < end; e += 16) {
            int s[16];
#pragma unroll
            for (int j = 0; j < 16; j++) s[j] = csr[e + j];
            u32 v[16];
#pragma unroll
            for (int j = 0; j < 16; j++) v[j] = *(const u32*)(Acat + (size_t)s[j] * 256 + 128 + fl);
#pragma unroll
            for (int j = 0; j < 16; j++) {
                m0 = fminf(m0, __uint_as_float(v[j] << 16));
                m1 = fminf(m1, __uint_as_float(v[j] & 0xffff0000u));
            }
        }
        for (; e + 3 < end; e += 4) {
            int s[4];
#pragma unroll
            for (int j = 0; j < 4; j++) s[j] = csr[e + j];
            u32 v[4];
#pragma unroll
            for (int j = 0; j < 4; j++) v[j] = *(const u32*)(Acat + (size_t)s[j] * 256 + 128 + fl);
#pragma unroll
            for (int j = 0; j < 4; j++) {
                m0 = fminf(m0, __uint_as_float(v[j] << 16));
                m1 = fminf(m1, __uint_as_float(v[j] & 0xffff0000u));
            }
        }
        for (; e < end; e++) {
            u32 v = *(const u32*)(Acat + (size_t)csr[e] * 256 + 128 + fl);
            m0 = fminf(m0, __uint_as_float(v << 16));
            m1 = fminf(m1, __uint_as_float(v & 0xffff0000u));
        }
        outv = (__float_as_uint(m0) >> 16) | (__float_as_uint(m1) & 0xffff0000u);
    }
    *(u32*)(Acat + (size_t)node * 256 + fl) = outv;
}

__global__ __launch_bounds__(256) void gather_min3_k(
    const float* __restrict__ feat, const int* __restrict__ ptr,
    const int* __restrict__ csr, float* __restrict__ agg, int n) {
    int i = blockIdx.x * 256 + threadIdx.x;
    if (i >= n) return;
    int e = ptr[i], end = ptr[i + 1];
    bool empty = (e == end);
    float m0 = FLTMAX, m1 = FLTMAX, m2 = FLTMAX;
    for (; e < end; e++) {
        const float* r = feat + (size_t)csr[e] * 3;
        m0 = fminf(m0, r[0]);
        m1 = fminf(m1, r[1]);
        m2 = fminf(m2, r[2]);
    }
    agg[(size_t)i * 3 + 0] = empty ? 0.f : m0;
    agg[(size_t)i * 3 + 1] = empty ? 0.f : m1;
    agg[(size_t)i * 3 + 2] = empty ? 0.f : m2;
}

// ====== convert bn_relu(h) (D=128) -> bf16 into A_cat right half ======
__global__ __launch_bounds__(256) void convert_k(
    const float* __restrict__ h, const float* __restrict__ coef,
    u16* __restrict__ Acat, int n) {
    int t = blockIdx.x * 256 + threadIdx.x;
    int total = n * 32;
    if (t >= total) return;
    int i = t >> 5;
    int dq = (t & 31) * 4;
    const float4 hv = *(const float4*)(h + (size_t)i * 128 + dq);
    const float4 ca = *(const float4*)(coef + dq);
    const float4 cb = *(const float4*)(coef + 128 + dq);
    ushort4 o;
    o.x = f2bf(trf(hv.x, ca.x, cb.x));
    o.y = f2bf(trf(hv.y, ca.y, cb.y));
    o.z = f2bf(trf(hv.z, ca.z, cb.z));
    o.w = f2bf(trf(hv.w, ca.w, cb.w));
    *(ushort4*)(Acat + (size_t)i * 256 + 128 + dq) = o;
}

// ====== weight prep: WT[c][k] = bf16( k<128 ? wl[k][c] : wr[k-128][c] ) ======
__global__ __launch_bounds__(256) void wprep_k(
    const float* __restrict__ wl, const float* __restrict__ wr,
    u16* __restrict__ WT, int N) {
    int t = blockIdx.x * 256 + threadIdx.x;
    if (t >= N * 256) return;
    int c = t >> 8;
    int k = t & 255;
    float v = (k < 128) ? wl[k * N + c] : wr[(k - 128) * N + c];
    WT[(size_t)c * 256 + k] = f2bf(v);
}

// ====== bf16 MFMA GEMM: out[n][128] = A_cat[n][256] @ W_cat[256][128] + bias ======
__global__ __launch_bounds__(256) void gemm_bf_k(
    const u16* __restrict__ A, const u16* __restrict__ WT,
    const float* __restrict__ bl1, const float* __restrict__ bl2,
    float* __restrict__ out, int n) {
    constexpr int NT = 8;
    const int tid = threadIdx.x;
    const int wave = tid >> 6, lane = tid & 63;
    const int quad = lane >> 4, l16 = lane & 15;
    const int row0 = blockIdx.x * 64 + wave * 16;
    const int rowA = min(row0 + l16, n - 1);
    const uint4* Arow = (const uint4*)(A + (size_t)rowA * 256) + quad;

    bf16x8 a[8];
#pragma unroll
    for (int kc = 0; kc < 8; kc++) {
        U16x8 u; u.u = Arow[kc * 4];
        a[kc] = u.b;
    }
    f32x4 acc[NT];
#pragma unroll
    for (int i = 0; i < NT; i++) acc[i] = (f32x4){0.f, 0.f, 0.f, 0.f};
#pragma unroll
    for (int nt = 0; nt < NT; nt++) {
        const uint4* Brow = (const uint4*)(WT + (size_t)(nt * 16 + l16) * 256) + quad;
#pragma unroll
        for (int kc = 0; kc < 8; kc++) {
            U16x8 u; u.u = Brow[kc * 4];
            acc[nt] = __builtin_amdgcn_mfma_f32_16x16x32_bf16(a[kc], u.b, acc[nt], 0, 0, 0);
        }
    }
#pragma unroll
    for (int nt = 0; nt < NT; nt++) {
        const int col = nt * 16 + l16;
        const float bias = (col < 64) ? bl1[col] : bl2[col - 64];
#pragma unroll
        for (int r = 0; r < 4; r++) {
            const int row = row0 + quad * 4 + r;
            if (row < n) out[(size_t)row * 128 + col] = acc[nt][r] + bias;
        }
    }
}

// ====== fp32 linear layer-1 (K=32 -> 128), LDS-staged A/h ======
__global__ __launch_bounds__(256) void linear1s_k(
    const float* __restrict__ agg, const float* __restrict__ h,
    const float* __restrict__ wl, const float* __restrict__ bl,
    const float* __restrict__ wr, float* __restrict__ out, int n) {
    constexpr int DOUT = 128, CT = 32, RB = 32, LDW = 36;
    __shared__ float Ash[RB * LDW];   // 4.6 KB
    __shared__ float Hsh[RB * LDW];   // 4.6 KB
    const int tid = threadIdx.x;
    const int base = blockIdx.x * RB;
    {   // stage: thread = (row = tid>>3, chunk = tid&7); col = chunk*4
        const int sr = tid >> 3;
        const int col = (tid & 7) * 4;
        const int grow = min(base + sr, n - 1);
        *(float4*)(Ash + sr * LDW + col) = *(const float4*)(agg + (size_t)grow * 32 + col);
        *(float4*)(Hsh + sr * LDW + col) = *(const float4*)(h + (size_t)grow * 32 + col);
    }
    __syncthreads();
    const int ct = tid % CT;
    const int rt = tid / CT;
    const int col = ct * 4;
    const int row0 = base + rt * 4;
    float4 acc[4] = {};
#pragma unroll 2
    for (int k0 = 0; k0 < 32; k0 += 4) {
        float4 wlv[4], wrv[4];
#pragma unroll
        for (int j = 0; j < 4; j++) {
            wlv[j] = *(const float4*)(wl + (size_t)(k0 + j) * DOUT + col);
            wrv[j] = *(const float4*)(wr + (size_t)(k0 + j) * DOUT + col);
        }
#pragma unroll
        for (int r = 0; r < 4; r++) {
            const float4 av = *(const float4*)(Ash + (rt * 4 + r) * LDW + k0);
            const float4 hv = *(const float4*)(Hsh + (rt * 4 + r) * LDW + k0);
#pragma unroll
            for (int j = 0; j < 4; j++) {
                const float aa = j == 0 ? av.x : j == 1 ? av.y : j == 2 ? av.z : av.w;
                const float bb = j == 0 ? hv.x : j == 1 ? hv.y : j == 2 ? hv.z : hv.w;
                acc[r].x += aa * wlv[j].x + bb * wrv[j].x;
                acc[r].y += aa * wlv[j].y + bb * wrv[j].y;
                acc[r].z += aa * wlv[j].z + bb * wrv[j].z;
                acc[r].w += aa * wlv[j].w + bb * wrv[j].w;
            }
        }
    }
    const float4 bv = *(const float4*)(bl + col);
#pragma unroll
    for (int r = 0; r < 4; r++) {
        if (row0 + r < n) {
            float4 o = acc[r];
            o.x += bv.x; o.y += bv.y; o.z += bv.z; o.w += bv.w;
            *(float4*)(out + (size_t)(row0 + r) * DOUT + col) = o;
        }
    }
}

// ====== fp32 linear (layer-2, K=128 -> 64), LDS-staged A/h (R9 win) ======
__global__ __launch_bounds__(256) void linear2_k(
    const float* __restrict__ agg, const float* __restrict__ h,
    const float* __restrict__ coef, const float* __restrict__ wl,
    const float* __restrict__ bl, const float* __restrict__ wr,
    float* __restrict__ out, int n) {
    constexpr int DIN = 128, DOUT = 64, CT = 16, RB = 64, LDW = 132;
    __shared__ float Ash[RB * LDW];
    __shared__ float Hsh[RB * LDW];
    const int tid = threadIdx.x;
    const int base = blockIdx.x * RB;
    {
        const int sr = tid >> 2;
        const int sc = tid & 3;
        const int grow = min(base + sr, n - 1);
        const float* ar = agg + (size_t)grow * DIN;
        const float* hr = h + (size_t)grow * DIN;
#pragma unroll
        for (int c = 0; c < 8; c++) {
            const int col = (sc + c * 4) * 4;
            const float4 av = *(const float4*)(ar + col);
            float4 hv = *(const float4*)(hr + col);
            const float4 ca = *(const float4*)(coef + col);
            const float4 cb = *(const float4*)(coef + DIN + col);
            hv.x = trf(hv.x, ca.x, cb.x); hv.y = trf(hv.y, ca.y, cb.y);
            hv.z = trf(hv.z, ca.z, cb.z); hv.w = trf(hv.w, ca.w, cb.w);
            *(float4*)(Ash + sr * LDW + col) = av;
            *(float4*)(Hsh + sr * LDW + col) = hv;
        }
    }
    __syncthreads();
    const int ct = tid % CT;
    const int rt = tid / CT;
    const int col = ct * 4;
    const int row0 = base + rt * 4;
    float4 acc[4] = {};
#pragma unroll 2
    for (int k0 = 0; k0 < DIN; k0 += 4) {
        float4 wlv[4], wrv[4];
#pragma unroll
        for (int j = 0; j < 4; j++) {
            wlv[j] = *(const float4*)(wl + (size_t)(k0 + j) * DOUT + col);
            wrv[j] = *(const float4*)(wr + (size_t)(k0 + j) * DOUT + col);
        }
#pragma unroll
        for (int r = 0; r < 4; r++) {
            const float4 av = *(const float4*)(Ash + (rt * 4 + r) * LDW + k0);
            const float4 hv = *(const float4*)(Hsh + (rt * 4 + r) * LDW + k0);
#pragma unroll
            for (int j = 0; j < 4; j++) {
                const float aa = j == 0 ? av.x : j == 1 ? av.y : j == 2 ? av.z : av.w;
                const float bb = j == 0 ? hv.x : j == 1 ? hv.y : j == 2 ? hv.z : hv.w;
                acc[r].x += aa * wlv[j].x + bb * wrv[j].x;
                acc[r].y += aa * wlv[j].y + bb * wrv[j].y;
                acc[r].z += aa * wlv[j].z + bb * wrv[j].z;
                acc[r].w += aa * wlv[j].w + bb * wrv[j].w;
            }
        }
    }
    const float4 bv = *(const float4*)(bl + col);
#pragma unroll
    for (int r = 0; r < 4; r++) {
        if (row0 + r < n) {
            float4 o = acc[r];
            o.x += bv.x; o.y += bv.y; o.z += bv.z; o.w += bv.w;
            *(float4*)(out + (size_t)(row0 + r) * DOUT + col) = o;
        }
    }
}

// ====== sh1 linear: concat([x(32), rm(3)]) -> 128, LDS-staged ======
__global__ __launch_bounds__(256) void linear_shs_k(
    const float* __restrict__ aggx, const float* __restrict__ x,
    const float* __restrict__ aggr, const float* __restrict__ rm,
    const float* __restrict__ wl, const float* __restrict__ bl,
    const float* __restrict__ wr, float* __restrict__ out, int n) {
    constexpr int DOUT = 128, CT = 32, RB = 32, LDW = 36;
    __shared__ float Ash[RB * LDW];
    __shared__ float Hsh[RB * LDW];
    __shared__ float Rsh[RB * 4], Msh[RB * 4];
    const int tid = threadIdx.x;
    const int base = blockIdx.x * RB;
    {
        const int sr = tid >> 3;
        const int col = (tid & 7) * 4;
        const int grow = min(base + sr, n - 1);
        *(float4*)(Ash + sr * LDW + col) = *(const float4*)(aggx + (size_t)grow * 32 + col);
        *(float4*)(Hsh + sr * LDW + col) = *(const float4*)(x + (size_t)grow * 32 + col);
        if (tid < RB) {
            const int gr = min(base + tid, n - 1);
#pragma unroll
            for (int k = 0; k < 3; k++) {
                Rsh[tid * 4 + k] = aggr[(size_t)gr * 3 + k];
                Msh[tid * 4 + k] = rm[(size_t)gr * 3 + k];
            }
        }
    }
    __syncthreads();
    const int ct = tid % CT;
    const int rt = tid / CT;
    const int col = ct * 4;
    const int row0 = base + rt * 4;
    float4 acc[4] = {};
#pragma unroll 2
    for (int k0 = 0; k0 < 32; k0 += 4) {
        float4 wlv[4], wrv[4];
#pragma unroll
        for (int j = 0; j < 4; j++) {
            wlv[j] = *(const float4*)(wl + (size_t)(k0 + j) * DOUT + col);
            wrv[j] = *(const float4*)(wr + (size_t)(k0 + j) * DOUT + col);
        }
#pragma unroll
        for (int r = 0; r < 4; r++) {
            const float4 av = *(const float4*)(Ash + (rt * 4 + r) * LDW + k0);
            const float4 hv = *(const float4*)(Hsh + (rt * 4 + r) * LDW + k0);
#pragma unroll
            for (int j = 0; j < 4; j++) {
                const float aa = j == 0 ? av.x : j == 1 ? av.y : j == 2 ? av.z : av.w;
                const float bb = j == 0 ? hv.x : j == 1 ? hv.y : j == 2 ? hv.z : hv.w;
                acc[r].x += aa * wlv[j].x + bb * wrv[j].x;
                acc[r].y += aa * wlv[j].y + bb * wrv[j].y;
                acc[r].z += aa * wlv[j].z + bb * wrv[j].z;
                acc[r].w += aa * wlv[j].w + bb * wrv[j].w;
            }
        }
    }
#pragma unroll
    for (int k = 0; k < 3; k++) {
        const float4 wlv = *(const float4*)(wl + (size_t)(32 + k) * DOUT + col);
        const float4 wrv = *(const float4*)(wr + (size_t)(32 + k) * DOUT + col);
#pragma unroll
        for (int r = 0; r < 4; r++) {
            const float a = Rsh[(rt * 4 + r) * 4 + k];
            const float b = Msh[(rt * 4 + r) * 4 + k];
            acc[r].x += a * wlv.x + b * wrv.x;
            acc[r].y += a * wlv.y + b * wrv.y;
            acc[r].z += a * wlv.z + b * wrv.z;
            acc[r].w += a * wlv.w + b * wrv.w;
        }
    }
    const float4 bv = *(const float4*)(bl + col);
#pragma unroll
    for (int r = 0; r < 4; r++) {
        if (row0 + r < n) {
            float4 o = acc[r];
            o.x += bv.x; o.y += bv.y; o.z += bv.z; o.w += bv.w;
            *(float4*)(out + (size_t)(row0 + r) * DOUT + col) = o;
        }
    }
}

// ---- per-column sum / sumsq with LDS pre-reduction ----
template <int D>
__global__ __launch_bounds__(256) void colstats_k(
    const float* __restrict__ x, float* __restrict__ stats, int total) {
    __shared__ float ls[256];
    int t0 = blockIdx.x * 256 + threadIdx.x;
    int stride = gridDim.x * 256;
    float s = 0.f, s2 = 0.f;
    for (int t = t0; t < total; t += stride) {
        float v = x[t];
        s += v;
        s2 += v * v;
    }
    int col = threadIdx.x % D;
    ls[threadIdx.x] = s;
    __syncthreads();
    if (threadIdx.x < D) {
        float a = s;
        for (int u = threadIdx.x + D; u < 256; u += D) a += ls[u];
        atomicAdd(&stats[col], a);
    }
    __syncthreads();
    ls[threadIdx.x] = s2;
    __syncthreads();
    if (threadIdx.x < D) {
        float a = s2;
        for (int u = threadIdx.x + D; u < 256; u += D) a += ls[u];
        atomicAdd(&stats[D + col], a);
    }
}

// ====== per-layer BN coefficients ======
template <int D>
__global__ void coef_k(const float* __restrict__ stats, const float* __restrict__ g,
                       const float* __restrict__ bb, float* __restrict__ coef,
                       float invN) {
    int d = threadIdx.x;
    if (d >= D) return;
    float mu = stats[d] * invN;
    float var = stats[D + d] * invN - mu * mu;
    float a = rsqrtf(var + 1e-5f) * g[d];
    coef[d] = a;
    coef[D + d] = bb[d] - mu * a;
}

__global__ void coef_dual_k(const float* __restrict__ stats,
                            const float* __restrict__ gR, const float* __restrict__ bR,
                            const float* __restrict__ gM, const float* __restrict__ bM,
                            float* __restrict__ coefR, float* __restrict__ coefM,
                            float invN) {
    int d = threadIdx.x;
    if (d >= 128) return;
    float mu = stats[d] * invN;
    float var = stats[128 + d] * invN - mu * mu;
    bool isR = d < 64;
    int c = isR ? d : d - 64;
    float g = isR ? gR[c] : gM[c];
    float be = isR ? bR[c] : bM[c];
    float a = rsqrtf(var + 1e-5f) * g;
    float* co = isR ? coefR : coefM;
    co[c] = a;
    co[64 + c] = be - mu * a;
}

// ====== rm head fused: gather(h2,D=64) + 64->3 linear + log_softmax + labels ======
__global__ __launch_bounds__(256) void rm_fused_k(
    const float* __restrict__ h2, const float* __restrict__ coef,
    const int* __restrict__ ptr, const int* __restrict__ csr,
    const float* __restrict__ wl, const float* __restrict__ bl,
    const float* __restrict__ wr, float* __restrict__ rmb,
    float* __restrict__ ls_out, float* __restrict__ lab, int n) {
    const int lane = threadIdx.x & 63;
    const int node = (blockIdx.x * 256 + threadIdx.x) >> 6;
    if (node >= n) return;
    const float a = coef[lane], b = coef[64 + lane];
    int e = ptr[node];
    const int end = ptr[node + 1];
    const bool empty = (e == end);
    float m = FLTMAX;
    for (; e + 15 < end; e += 16) {
        int s[16];
#pragma unroll
        for (int j = 0; j < 16; j++) s[j] = csr[e + j];
        float v[16];
#pragma unroll
        for (int j = 0; j < 16; j++) v[j] = h2[(size_t)s[j] * 64 + lane];
#pragma unroll
        for (int j = 0; j < 16; j++) m = fminf(m, trf(v[j], a, b));
    }
    for (; e + 3 < end; e += 4) {
        int s[4];
#pragma unroll
        for (int j = 0; j < 4; j++) s[j] = csr[e + j];
        float v[4];
#pragma unroll
        for (int j = 0; j < 4; j++) v[j] = h2[(size_t)s[j] * 64 + lane];
#pragma unroll
        for (int j = 0; j < 4; j++) m = fminf(m, trf(v[j], a, b));
    }
    for (; e < end; e++) m = fminf(m, trf(h2[(size_t)csr[e] * 64 + lane], a, b));
    m = empty ? 0.f : m;
    const float hv = trf(h2[(size_t)node * 64 + lane], a, b);
    float c0 = m * wl[lane * 3 + 0] + hv * wr[lane * 3 + 0];
    float c1 = m * wl[lane * 3 + 1] + hv * wr[lane * 3 + 1];
    float c2 = m * wl[lane * 3 + 2] + hv * wr[lane * 3 + 2];
#pragma unroll
    for (int off = 1; off < 64; off <<= 1) {
        c0 += __shfl_xor(c0, off);
        c1 += __shfl_xor(c1, off);
        c2 += __shfl_xor(c2, off);
    }
    const float r0 = c0 + bl[0], r1 = c1 + bl[1], r2 = c2 + bl[2];
    if (lane < 3) {
        const float r = lane == 0 ? r0 : lane == 1 ? r1 : r2;
        rmb[(size_t)node * 3 + lane] = r;
        const float mx = fmaxf(r0, fmaxf(r1, r2));
        const float lse = mx + logf(expf(r0 - mx) + expf(r1 - mx) + expf(r2 - mx));
        ls_out[(size_t)node * 3 + lane] = r - lse;
        if (lane == 0) lab[node] = (r2 > r0 && r2 > r1) ? 1.f : 0.f;
    }
}

// ====== final heads: rtmd[n][128] (rt|md) with fused BN+ReLU ======
__global__ __launch_bounds__(256) void final_k(
    const float* __restrict__ rtmd,
    const float* __restrict__ cR, const float* __restrict__ cM,
    const float* __restrict__ rtw, const float* __restrict__ rtb,
    const float* __restrict__ mdw, const float* __restrict__ mdb,
    const float* __restrict__ lab, float* __restrict__ out_rt,
    float* __restrict__ out_md, int n) {
    int i = blockIdx.x * 256 + threadIdx.x;
    if (i >= n) return;
    const float* rr = rtmd + (size_t)i * 128;
    const float* mr = rr + 64;
    float a = rtb[0], b = mdb[0];
#pragma unroll 8
    for (int k = 0; k < 64; k++) {
        a += trf(rr[k], cR[k], cR[64 + k]) * rtw[k];
        b += trf(mr[k], cM[k], cM[64 + k]) * mdw[k];
    }
    float l = lab[i];
    out_rt[i] = a * l;
    out_md[i] = b * l;
}

extern "C" void kernel_launch(void* const* d_in, const int* in_sizes, int n_in,
                              void* d_out, int out_size, void* d_ws, size_t ws_size,
                              hipStream_t stream) {
    const float* x = (const float*)d_in[0];
    const int* ei = (const int*)d_in[1];
    const int E = in_sizes[1] / 2;
    const int n = in_sizes[0] / 32;
    const int* src = ei;
    const int* dst = ei + E;

    const float* rm1_wl = (const float*)d_in[2];
    const float* rm1_bl = (const float*)d_in[3];
    const float* rm1_wr = (const float*)d_in[4];
    const float* rmn1_g = (const float*)d_in[5];
    const float* rmn1_b = (const float*)d_in[6];
    const float* rm2_wl = (const float*)d_in[7];
    const float* rm2_bl = (const float*)d_in[8];
    const float* rm2_wr = (const float*)d_in[9];
    const float* rmn2_g = (const float*)d_in[10];
    const float* rmn2_b = (const float*)d_in[11];
    const float* rm4_wl = (const float*)d_in[12];
    const float* rm4_bl = (const float*)d_in[13];
    const float* rm4_wr = (const float*)d_in[14];
    const float* sh1_wl = (const float*)d_in[15];
    const float* sh1_bl = (const float*)d_in[16];
    const float* sh1_wr = (const float*)d_in[17];
    const float* shn1_g = (const float*)d_in[18];
    const float* shn1_b = (const float*)d_in[19];
    const float* rt1_wl = (const float*)d_in[20];
    const float* rt1_bl = (const float*)d_in[21];
    const float* rt1_wr = (const float*)d_in[22];
    const float* rtn1_g = (const float*)d_in[23];
    const float* rtn1_b = (const float*)d_in[24];
    const float* rt3_w = (const float*)d_in[25];
    const float* rt3_b = (const float*)d_in[26];
    const float* md1_wl = (const float*)d_in[27];
    const float* md1_bl = (const float*)d_in[28];
    const float* md1_wr = (const float*)d_in[29];
    const float* mdn1_g = (const float*)d_in[30];
    const float* mdn1_b = (const float*)d_in[31];
    const float* md3_w = (const float*)d_in[32];
    const float* md3_b = (const float*)d_in[33];

    // workspace layout; shbuf serves as fp32 aggB (layer 2), then bf16 Acat (dual)
    char* w = (char*)d_ws;
    float* aggX  = (float*)w; w += (size_t)n * 32 * 4;
    float* h1    = (float*)w; w += (size_t)n * 128 * 4;   // h1 raw, later h3 raw
    char*  shbuf = w;         w += (size_t)n * 512;       // aggB fp32 [n][128] | Acat bf16 [n][256]
    float* h2rt  = (float*)w; w += (size_t)n * 128 * 4;   // h2 [n][64], later rtmd [n][128]
    float* rmb   = (float*)w; w += (size_t)n * 3 * 4;
    float* aggR  = (float*)w; w += (size_t)n * 3 * 4;
    float* lab   = (float*)w; w += (size_t)n * 4;
    float* stats = (float*)w; w += 1024 * 4;
    float* coef  = (float*)w; w += 1024 * 4;
    u16*   WTD   = (u16*)w;   w += (size_t)128 * 256 * 2;
    int* ptr  = (int*)w; w += (size_t)(n + 1) * 4;
    int* pos  = (int*)w; w += (size_t)n * 4;
    int* bsum = (int*)w; w += 1024 * 4;
    int* csr  = (int*)w; w += (size_t)E * 4;

    float* aggB = (float*)shbuf;
    u16*   Acat = (u16*)shbuf;
    float* h2 = h2rt;
    float* rtmd = h2rt;
    float* stats1 = stats, *stats2 = stats + 256, *statsSh = stats + 512, *statsD = stats + 768;
    float* coef1 = coef, *coef2 = coef + 256, *coefSh = coef + 384;
    float* coefRt = coef + 640, *coefMd = coef + 768;

    float* out = (float*)d_out;
    float* out_ls = out;
    float* out_rt = out + (size_t)3 * n;
    float* out_md = out + (size_t)4 * n;

    const float invN = 1.f / (float)n;
    auto cdiv = [](int a, int b) { return (a + b - 1) / b; };
    const int nb = cdiv(n, 256);

    hipMemsetAsync(stats, 0, 1024 * 4, stream);
    hipMemsetAsync(pos, 0, (size_t)n * 4, stream);

    // ---- CSR build + dual-weight prep (feature-independent)
    hist_k<<<cdiv(E, 256), 256, 0, stream>>>(dst, pos, E);
    wprep_k<<<64, 256, 0, stream>>>(rt1_wl, rt1_wr, WTD, 64);
    wprep_k<<<64, 256, 0, stream>>>(md1_wl, md1_wr, WTD + (size_t)64 * 256, 64);
    scan_block_k<<<nb, 256, 0, stream>>>(pos, ptr, bsum, n);
    scan_bsum_k<<<1, 512, 0, stream>>>(bsum, nb);
    scan_add_k<<<nb, 256, 0, stream>>>(ptr, pos, bsum, n, E);
    csr_fill_part_k<<<cdiv(E, 256) * 8, 256, 0, stream>>>(src, dst, pos, csr, E, cdiv(n, 8));

    // ---- layer 1 (fp32): agg(x) -> linear -> h1; stats -> coef1
    gather_min32_k<<<cdiv(n, 8), 256, 0, stream>>>(x, ptr, csr, aggX, n);
    linear1s_k<<<cdiv(n, 32), 256, 0, stream>>>(aggX, x, rm1_wl, rm1_bl, rm1_wr, h1, n);
    colstats_k<128><<<256, 256, 0, stream>>>(h1, stats1, n * 128);
    coef_k<128><<<1, 128, 0, stream>>>(stats1, rmn1_g, rmn1_b, coef1, invN);

    // ---- layer 2 (fp32, label-critical): gather(bnrelu(h1)) -> linear -> h2
    gather_min128_k<<<cdiv(n, 4), 256, 0, stream>>>(h1, ptr, csr, coef1, aggB, n);
    linear2_k<<<cdiv(n, 64), 256, 0, stream>>>(aggB, h1, coef1, rm2_wl, rm2_bl, rm2_wr, h2, n);
    colstats_k<64><<<256, 256, 0, stream>>>(h2, stats2, n * 64);
    coef_k<64><<<1, 64, 0, stream>>>(stats2, rmn2_g, rmn2_b, coef2, invN);

    // ---- rm head (fp32): fused gather + linear + log_softmax + labels
    rm_fused_k<<<cdiv(n, 4), 256, 0, stream>>>(h2, coef2, ptr, csr, rm4_wl, rm4_bl, rm4_wr, rmb, out_ls, lab, n);

    // ---- sh1 (fp32): agg(rm); linear concat([x,rm]) -> h3 (h1 buf); stats -> coefSh
    gather_min3_k<<<cdiv(n, 256), 256, 0, stream>>>(rmb, ptr, csr, aggR, n);
    linear_shs_k<<<cdiv(n, 32), 256, 0, stream>>>(aggX, x, aggR, rmb, sh1_wl, sh1_bl, sh1_wr, h1, n);
    colstats_k<128><<<256, 256, 0, stream>>>(h1, statsSh, n * 128);
    coef_k<128><<<1, 128, 0, stream>>>(statsSh, shn1_g, shn1_b, coefSh, invN);

    // ---- dual rt/md (bf16 MFMA, continuous path):
    convert_k<<<cdiv(n * 32, 256), 256, 0, stream>>>(h1, coefSh, Acat, n);
    gather_bf_k<<<cdiv(n, 4), 256, 0, stream>>>(Acat, ptr, csr, n);
    gemm_bf_k<<<cdiv(n, 64), 256, 0, stream>>>(Acat, WTD, rt1_bl, md1_bl, rtmd, n);
    colstats_k<128><<<256, 256, 0, stream>>>(rtmd, statsD, n * 128);
    coef_dual_k<<<1, 128, 0, stream>>>(statsD, rtn1_g, rtn1_b, mdn1_g, mdn1_b, coefRt, coefMd, invN);

    // ---- final heads
    final_k<<<cdiv(n, 256), 256, 0, stream>>>(rtmd, coefRt, coefMd,
                                              rt3_w, rt3_b, md3_w, md3_b, lab,
                                              out_rt, out_md, n);
}